// Round 10
// baseline (1506.189 us; speedup 1.0000x reference)
//
#include <hip/hip_runtime.h>
#include <math.h>

#define NTOK 32768
#define NDIM 512
#define NCODE 4096
#define NPANEL 16
#define PSZ 256

// output layout (flat f32, reference tuple order)
#define OFF_Z      0
#define OFF_DIFF   16777216
#define OFF_CODES  16777217
#define OFF_EMB    16809985
#define OFF_SIZE   18907137
#define OFF_SUM    18911233
#define OFF_AVGU   21008385
#define OFF_USAGE  21008386
#define OFF_ENT    21008387

#define TAU 0.01f

typedef _Float16 f16x8 __attribute__((ext_vector_type(8)));
typedef float f32x4 __attribute__((ext_vector_type(4)));
typedef unsigned short ushort8 __attribute__((ext_vector_type(8)));
typedef unsigned int u32;

__device__ __forceinline__ void atomAddF(float* p, float v) {
  unsafeAtomicAdd(p, v);
}

__device__ __forceinline__ void gload16(const void* g, void* l) {
  __builtin_amdgcn_global_load_lds((const __attribute__((address_space(1))) u32*)g,
                                   (__attribute__((address_space(3))) u32*)l, 16, 0, 0);
}

// involutive 16B-chunk swizzle: bits0-2 ^= bits3-5
__device__ __forceinline__ int swz16(int c) { return c ^ ((c >> 3) & 7); }

// merge other top-2 pair into (d1,i1,d2,i2); index tiebreak = lower wins
__device__ __forceinline__ void mergePair(float& d1, int& i1, float& d2, int& i2,
                                          float od1, int oi1, float od2, int oi2) {
  bool oF = (od1 < d1) || (od1 == d1 && oi1 < i1);
  float w1 = oF ? od1 : d1;  int wi1 = oF ? oi1 : i1;
  float l1 = oF ? d1 : od1;  int li1 = oF ? i1 : oi1;
  bool c = (od2 < d2) || (od2 == d2 && oi2 < i2);
  float c2 = c ? od2 : d2;   int ci2 = c ? oi2 : i2;
  bool lb = (l1 < c2) || (l1 == c2 && li1 < ci2);
  d2 = lb ? l1 : c2; i2 = lb ? li1 : ci2;
  d1 = w1; i1 = wi1;
}

__global__ void k_zero(float* __restrict__ p, int n) {
  int i = blockIdx.x * blockDim.x + threadIdx.x;
  if (i < n) p[i] = 0.0f;
}

// fused prep: blocks [0,8192) split x; blocks [8192,9216) do emb rowsq+split (+ws zero)
__global__ void k_prep(const float* __restrict__ x, const float* __restrict__ emb,
                       unsigned short* __restrict__ xh, unsigned short* __restrict__ xl,
                       unsigned short* __restrict__ eh, unsigned short* __restrict__ el,
                       float* __restrict__ e2, float* __restrict__ wsZero) {
  int b = blockIdx.x, tid = threadIdx.x;
  if (b < 8192) {
    int i = b * 256 + tid;
    const float4* p = (const float4*)(x + (size_t)i * 8);
    float4 a = p[0], bb = p[1];
    float v[8] = {a.x, a.y, a.z, a.w, bb.x, bb.y, bb.z, bb.w};
    ushort8 h, lw;
    #pragma unroll
    for (int j = 0; j < 8; j++) {
      float f = v[j];
      _Float16 hb = (_Float16)f;
      float hf = (float)hb;
      _Float16 lb = (_Float16)(f - hf);
      h[j]  = __builtin_bit_cast(unsigned short, hb);
      lw[j] = __builtin_bit_cast(unsigned short, lb);
    }
    *(ushort8*)(xh + (size_t)i * 8) = h;
    *(ushort8*)(xl + (size_t)i * 8) = lw;
    return;
  }
  int be = b - 8192;
  if (be < 17) {
    int i = be * 256 + tid;
    if (i < 4160) wsZero[i] = 0.0f;
  }
  int w    = tid >> 6;
  int lane = tid & 63;
  int row  = be * 4 + w;
  const float* r = emb + (size_t)row * NDIM + lane * 8;
  float4 a = *(const float4*)r;
  float4 bb = *(const float4*)(r + 4);
  float v[8] = {a.x, a.y, a.z, a.w, bb.x, bb.y, bb.z, bb.w};
  ushort8 h, lw;
  float sq = 0.0f;
  #pragma unroll
  for (int j = 0; j < 8; j++) {
    float f = v[j];
    sq += f * f;
    _Float16 hb = (_Float16)f;
    float hf = (float)hb;
    _Float16 lb = (_Float16)(f - hf);
    h[j]  = __builtin_bit_cast(unsigned short, hb);
    lw[j] = __builtin_bit_cast(unsigned short, lb);
  }
  size_t o = (size_t)row * NDIM + lane * 8;
  *(ushort8*)(eh + o) = h;
  *(ushort8*)(el + o) = lw;
  #pragma unroll
  for (int off = 32; off >= 1; off >>= 1) sq += __shfl_xor(sq, off, 64);
  if (lane == 0) e2[row] = sq;
}

// one wave per row: sum of squares (fallback path only)
__global__ void k_rowsq(const float* __restrict__ rows, float* __restrict__ out, int nrows) {
  int gw   = (blockIdx.x * blockDim.x + threadIdx.x) >> 6;
  int lane = threadIdx.x & 63;
  if (gw >= nrows) return;
  const float* r = rows + (size_t)gw * NDIM + lane * 8;
  float4 a = *(const float4*)r;
  float4 b = *(const float4*)(r + 4);
  float s = ((a.x*a.x + a.y*a.y) + (a.z*a.z + a.w*a.w))
          + ((b.x*b.x + b.y*b.y) + (b.z*b.z + b.w*b.w));
  #pragma unroll
  for (int off = 32; off >= 1; off >>= 1) s += __shfl_xor(s, off, 64);
  if (lane == 0) out[gw] = s;
}

// ===================== MFMA argmin (r7 mapping + counted-vmcnt pipeline) =====================
// grid 256: p = hw&15 (fixed 256-code panel), s = hw>>4 (2048-token subrange, 8 chunks of 256).
// 8 waves: wm 0..3 (64 token rows) x wn 0..1 (128 code cols). acc tile 256x256 per chunk.
// dist = e2 - 2*dot; dot = hh + hl + lh (3 f16 MFMAs). Per-chunk top-2 flush to panel partials.
// K-step schedule (T4): STAGE(next); vmcnt(8); s_barrier; ds_read+MFMA; s_barrier.
// Loads stay in flight across barriers (no vmcnt(0) drain in the hot loop).
#define SLOT 8192   // ushorts per LDS buffer (256 rows x 32 k)
__launch_bounds__(512, 2)
__global__ void k_argmin_mfma(const unsigned short* __restrict__ xh, const unsigned short* __restrict__ xl,
                              const unsigned short* __restrict__ eh, const unsigned short* __restrict__ el,
                              const float* __restrict__ e2,
                              float* __restrict__ pd1, int* __restrict__ pi1,
                              float* __restrict__ pd2, int* __restrict__ pi2) {
  __shared__ __align__(16) unsigned short Ah[2 * SLOT];
  __shared__ __align__(16) unsigned short Al[2 * SLOT];
  __shared__ __align__(16) unsigned short Bh[2 * SLOT];
  __shared__ __align__(16) unsigned short Bl[2 * SLOT];
  __shared__ float redD1[512];
  __shared__ int   redI1[512];
  __shared__ float redD2[512];
  __shared__ int   redI2[512];

  const int tid = threadIdx.x;
  const int w   = tid >> 6;
  const int l   = tid & 63;
  const int wm  = w >> 1;     // 0..3: 64-row token group
  const int wn  = w & 1;      // 0..1: 128-col code group
  const int l15 = l & 15;
  const int l4  = l >> 4;

  const int p      = blockIdx.x & 15;
  const int s      = blockIdx.x >> 4;
  const int cbase  = p * PSZ;
  const int tbase0 = s * 2048;

  // fragment LDS offsets (ushort units), swizzled
  int aOff[4], bOff[8];
  #pragma unroll
  for (int mi = 0; mi < 4; mi++) aOff[mi] = swz16(((wm * 64 + mi * 16 + l15) << 2) | l4) * 8;
  #pragma unroll
  for (int nj = 0; nj < 8; nj++) bOff[nj] = swz16(((wn * 128 + nj * 16 + l15) << 2) | l4) * 8;

  // hoisted e2 values (code cols fixed per block)
  float ev[8];
  #pragma unroll
  for (int nj = 0; nj < 8; nj++) ev[nj] = e2[cbase + wn * 128 + nj * 16 + l15];

  // staging: linear LDS chunks {tid, tid+512}; swizzled (row,seg) source (involution)
  int sR[2], sS[2];
  #pragma unroll
  for (int q = 0; q < 2; q++) {
    int sc = swz16(tid + q * 512);
    sR[q] = sc >> 2; sS[q] = (sc & 3) * 8;
  }

  auto STAGE = [&](int buf, int tbase, int k0) {
    #pragma unroll
    for (int q = 0; q < 2; q++) {
      int dst = (tid + q * 512) * 8;
      size_t aGq = (size_t)(tbase + sR[q]) * NDIM + k0 + sS[q];
      gload16(xh + aGq, Ah + buf * SLOT + dst);
      gload16(xl + aGq, Al + buf * SLOT + dst);
      size_t bGq = (size_t)(cbase + sR[q]) * NDIM + k0 + sS[q];
      gload16(eh + bGq, Bh + buf * SLOT + dst);
      gload16(el + bGq, Bl + buf * SLOT + dst);
    }
  };

  STAGE(0, tbase0, 0);
  int cur = 0;

  for (int ci = 0; ci < 8; ci++) {
    const int tbase = tbase0 + ci * 256;
    f32x4 acc[4][8];
    #pragma unroll
    for (int mi = 0; mi < 4; mi++)
      #pragma unroll
      for (int nj = 0; nj < 8; nj++) acc[mi][nj] = (f32x4)0.0f;

    for (int kt = 0; kt < 16; kt++) {
      bool issued = true;
      if (kt < 15)     STAGE(cur ^ 1, tbase, (kt + 1) * 32);
      else if (ci < 7) STAGE(cur ^ 1, tbase + 256, 0);
      else             issued = false;

      // wait only for the PREVIOUS step's 8 loads (the cur buffer), not the 8 just issued
      if (issued) asm volatile("s_waitcnt vmcnt(8)" ::: "memory");
      else        asm volatile("s_waitcnt vmcnt(0)" ::: "memory");
      __builtin_amdgcn_s_barrier();   // everyone's cur-buffer staging complete

      const unsigned short* AhC = Ah + cur * SLOT;
      const unsigned short* AlC = Al + cur * SLOT;
      const unsigned short* BhC = Bh + cur * SLOT;
      const unsigned short* BlC = Bl + cur * SLOT;

      f16x8 ah[4], al[4];
      #pragma unroll
      for (int mi = 0; mi < 4; mi++) {
        ah[mi] = *(const f16x8*)(const void*)(AhC + aOff[mi]);
        al[mi] = *(const f16x8*)(const void*)(AlC + aOff[mi]);
      }
      #pragma unroll
      for (int nj = 0; nj < 8; nj++) {
        f16x8 bh = *(const f16x8*)(const void*)(BhC + bOff[nj]);
        f16x8 bl = *(const f16x8*)(const void*)(BlC + bOff[nj]);
        #pragma unroll
        for (int mi = 0; mi < 4; mi++) {
          acc[mi][nj] = __builtin_amdgcn_mfma_f32_16x16x32_f16(ah[mi], bh, acc[mi][nj], 0, 0, 0);
          acc[mi][nj] = __builtin_amdgcn_mfma_f32_16x16x32_f16(ah[mi], bl, acc[mi][nj], 0, 0, 0);
          acc[mi][nj] = __builtin_amdgcn_mfma_f32_16x16x32_f16(al[mi], bh, acc[mi][nj], 0, 0, 0);
        }
      }
      __builtin_amdgcn_s_barrier();   // everyone done reading cur -> next step may overwrite it
      cur ^= 1;
    }

    // per-chunk top-2 over this block's 256-code panel
    float d1[16], d2[16];
    int   i1[16], i2[16];
    #pragma unroll
    for (int t = 0; t < 16; t++) { d1[t] = 1e30f; d2[t] = 1e30f; i1[t] = 0; i2[t] = 0; }
    #pragma unroll
    for (int nj = 0; nj < 8; nj++) {
      int col = cbase + wn * 128 + nj * 16 + l15;
      #pragma unroll
      for (int mi = 0; mi < 4; mi++) {
        #pragma unroll
        for (int r = 0; r < 4; r++) {
          float d = ev[nj] - 2.0f * acc[mi][nj][r];
          int t = mi * 4 + r;
          if (d < d1[t]) { d2[t] = d1[t]; i2[t] = i1[t]; d1[t] = d; i1[t] = col; }
          else if (d < d2[t]) { d2[t] = d; i2[t] = col; }
        }
      }
    }
    // butterfly over the 16 column-lanes
    #pragma unroll
    for (int off = 8; off >= 1; off >>= 1) {
      #pragma unroll
      for (int t = 0; t < 16; t++) {
        float od1 = __shfl_xor(d1[t], off, 16);
        int   oi1 = __shfl_xor(i1[t], off, 16);
        float od2 = __shfl_xor(d2[t], off, 16);
        int   oi2 = __shfl_xor(i2[t], off, 16);
        mergePair(d1[t], i1[t], d2[t], i2[t], od1, oi1, od2, oi2);
      }
    }
    if (l15 == 0) {
      #pragma unroll
      for (int t = 0; t < 16; t++) {
        int rowLocal = wm * 64 + (t >> 2) * 16 + l4 * 4 + (t & 3);
        redD1[wn * 256 + rowLocal] = d1[t];
        redI1[wn * 256 + rowLocal] = i1[t];
        redD2[wn * 256 + rowLocal] = d2[t];
        redI2[wn * 256 + rowLocal] = i2[t];
      }
    }
    __syncthreads();
    if (tid < 256) {
      float a1 = redD1[tid], a2 = redD2[tid];
      int   x1 = redI1[tid], x2 = redI2[tid];
      mergePair(a1, x1, a2, x2, redD1[256 + tid], redI1[256 + tid], redD2[256 + tid], redI2[256 + tid]);
      size_t o = (size_t)p * NTOK + tbase + tid;
      pd1[o] = a1; pi1[o] = x1; pd2[o] = a2; pi2[o] = x2;
    }
    __syncthreads();
  }
}

// merge the 16 panel partials -> idxArr, i2Arr; pair-recheck flagged tokens in-block (f64)
__global__ void k_combine_recheck(const float* __restrict__ pd1, const int* __restrict__ pi1,
                                  const float* __restrict__ pd2, const int* __restrict__ pi2,
                                  const float* __restrict__ x, const float* __restrict__ emb,
                                  int* __restrict__ idxArr) {
  __shared__ int fT[256], fC1[256], fC2[256];
  __shared__ int fcnt;
  int tid = threadIdx.x;
  int t   = blockIdx.x * 256 + tid;
  if (tid == 0) fcnt = 0;
  __syncthreads();

  float a1 = pd1[t], a2 = pd2[t];
  int   x1 = pi1[t], x2 = pi2[t];
  #pragma unroll
  for (int k = 1; k < NPANEL; k++) {
    size_t o = (size_t)k * NTOK + t;
    mergePair(a1, x1, a2, x2, pd1[o], pi1[o], pd2[o], pi2[o]);
  }
  idxArr[t] = x1;
  if (a2 - a1 < TAU) {
    int slot = atomicAdd(&fcnt, 1);
    fT[slot] = t; fC1[slot] = x1; fC2[slot] = x2;
  }
  __syncthreads();

  int n  = fcnt;
  int wv = tid >> 6, lane = tid & 63;
  for (int ti = wv; ti < n; ti += 4) {
    int tt = fT[ti], c1 = fC1[ti], c2 = fC2[ti];
    const float* xr = x   + (size_t)tt * NDIM + lane * 8;
    const float* e1 = emb + (size_t)c1 * NDIM + lane * 8;
    const float* e2 = emb + (size_t)c2 * NDIM + lane * 8;
    double s1 = 0.0, s2 = 0.0;
    #pragma unroll
    for (int j = 0; j < 8; j++) {
      double xv = (double)xr[j];
      double a = (double)e1[j];
      double b = (double)e2[j];
      s1 += a * (a - 2.0 * xv);
      s2 += b * (b - 2.0 * xv);
    }
    #pragma unroll
    for (int off = 32; off >= 1; off >>= 1) {
      s1 += __shfl_xor(s1, off, 64);
      s2 += __shfl_xor(s2, off, 64);
    }
    if (lane == 0) {
      bool take2 = (s2 < s1) || (s2 == s1 && c2 < c1);
      if (take2) idxArr[tt] = c2;
    }
  }
}

// ===================== fallback f32 argmin (small-ws path) =====================
#define BM 64
#define BN 64
#define BK 32
__launch_bounds__(256)
__global__ void k_argmin_f32(const float* __restrict__ x, const float* __restrict__ emb,
                             const float* __restrict__ e2, int* __restrict__ idxOut) {
  __shared__ __align__(16) float xs[BK][BM + 4];
  __shared__ __align__(16) float es[BK][BN + 4];
  const int tid  = threadIdx.x;
  const int tx   = tid & 15;
  const int ty   = tid >> 4;
  const int brow = blockIdx.x * BM;
  const int lk   = tid & 7;
  const int lr   = tid >> 3;

  double best[4];
  int    bidx[4];
  #pragma unroll
  for (int i = 0; i < 4; i++) { best[i] = 1e300; bidx[i] = 0; }

  for (int c0 = 0; c0 < NCODE; c0 += BN) {
    float acc[4][4];
    #pragma unroll
    for (int i = 0; i < 4; i++)
      #pragma unroll
      for (int j = 0; j < 4; j++) acc[i][j] = 0.0f;
    for (int k0 = 0; k0 < NDIM; k0 += BK) {
      __syncthreads();
      float4 v0 = *(const float4*)&x  [(size_t)(brow + lr)      * NDIM + k0 + lk * 4];
      float4 v1 = *(const float4*)&x  [(size_t)(brow + lr + 32) * NDIM + k0 + lk * 4];
      float4 w0 = *(const float4*)&emb[(size_t)(c0   + lr)      * NDIM + k0 + lk * 4];
      float4 w1 = *(const float4*)&emb[(size_t)(c0   + lr + 32) * NDIM + k0 + lk * 4];
      float a0[4] = {v0.x, v0.y, v0.z, v0.w};
      float a1[4] = {v1.x, v1.y, v1.z, v1.w};
      float b0[4] = {w0.x, w0.y, w0.z, w0.w};
      float b1f[4] = {w1.x, w1.y, w1.z, w1.w};
      #pragma unroll
      for (int j = 0; j < 4; j++) {
        xs[lk * 4 + j][lr]      = a0[j];
        xs[lk * 4 + j][lr + 32] = a1[j];
        es[lk * 4 + j][lr]      = b0[j];
        es[lk * 4 + j][lr + 32] = b1f[j];
      }
      __syncthreads();
      #pragma unroll
      for (int k = 0; k < BK; k++) {
        const float4 av = *(const float4*)&xs[k][ty * 4];
        const float4 bv = *(const float4*)&es[k][tx * 4];
        const float ax[4] = {av.x, av.y, av.z, av.w};
        const float bx[4] = {bv.x, bv.y, bv.z, bv.w};
        #pragma unroll
        for (int i = 0; i < 4; i++)
          #pragma unroll
          for (int j = 0; j < 4; j++) acc[i][j] += ax[i] * bx[j];
      }
    }
    #pragma unroll
    for (int j = 0; j < 4; j++) {
      float e2v = e2[c0 + tx * 4 + j];
      int   ci  = c0 + tx * 4 + j;
      #pragma unroll
      for (int i = 0; i < 4; i++) {
        double d = (double)e2v - 2.0 * (double)acc[i][j];
        if (d < best[i]) { best[i] = d; bidx[i] = ci; }
      }
    }
  }
  #pragma unroll
  for (int off = 8; off >= 1; off >>= 1) {
    #pragma unroll
    for (int i = 0; i < 4; i++) {
      double ob = __shfl_xor(best[i], off, 16);
      int    oi = __shfl_xor(bidx[i], off, 16);
      if (ob < best[i] || (ob == best[i] && oi < bidx[i])) { best[i] = ob; bidx[i] = oi; }
    }
  }
  if (tx == 0) {
    #pragma unroll
    for (int i = 0; i < 4; i++) idxOut[brow + ty * 4 + i] = bidx[i];
  }
}

// one wave per token: z, diff partial, int histogram, codes
__global__ void k_z(const float* __restrict__ x, const float* __restrict__ emb,
                    const int* __restrict__ idxArr, float* __restrict__ z,
                    float* __restrict__ diffSum, int* __restrict__ histI,
                    float* __restrict__ codesOut) {
  int t    = (blockIdx.x * blockDim.x + threadIdx.x) >> 6;
  int lane = threadIdx.x & 63;
  if (t >= NTOK) return;
  int idx = idxArr[t];
  const float* xr = x   + (size_t)t   * NDIM;
  const float* er = emb + (size_t)idx * NDIM;
  float* zr = z + (size_t)t * NDIM;
  float part = 0.0f;
  #pragma unroll
  for (int b = 0; b < 2; b++) {
    int k = lane * 8 + b * 4;
    float4 q  = *(const float4*)(er + k);
    float4 xv = *(const float4*)(xr + k);
    float4 dv; dv.x = q.x - xv.x; dv.y = q.y - xv.y; dv.z = q.z - xv.z; dv.w = q.w - xv.w;
    float4 zv; zv.x = xv.x + dv.x; zv.y = xv.y + dv.y; zv.z = xv.z + dv.z; zv.w = xv.w + dv.w;
    *(float4*)(zr + k) = zv;
    part += ((dv.x*dv.x + dv.y*dv.y) + (dv.z*dv.z + dv.w*dv.w));
  }
  #pragma unroll
  for (int off = 32; off >= 1; off >>= 1) part += __shfl_xor(part, off, 64);
  if (lane == 0) {
    atomAddF(diffSum, part);
    atomicAdd(histI + idx, 1);
    codesOut[t] = (float)idx;
  }
}

// single block: prefix-scan over hist + new_size/scalars
__global__ void k_scanstats(const int* __restrict__ histI, int* __restrict__ offs,
                            int* __restrict__ cursor, const float* __restrict__ clusterSize,
                            const float* __restrict__ diffSum, float* __restrict__ out,
                            float* __restrict__ nOut) {
  __shared__ int part[256];
  int tid = threadIdx.x;
  int base = tid * 16;
  int local[16];
  int s = 0;
  #pragma unroll
  for (int j = 0; j < 16; j++) { local[j] = s; s += histI[base + j]; }
  part[tid] = s;
  __syncthreads();
  for (int off = 1; off < 256; off <<= 1) {
    int v = 0;
    if (tid >= off) v = part[tid - off];
    __syncthreads();
    part[tid] += v;
    __syncthreads();
  }
  int pre = (tid == 0) ? 0 : part[tid - 1];
  #pragma unroll
  for (int j = 0; j < 16; j++) {
    int o = pre + local[j];
    offs[base + j]   = o;
    cursor[base + j] = o;
  }

  const float OMD = (float)(1.0 - 0.995);
  float ln = 0.0f, lu = 0.0f, le = 0.0f;
  for (int i = tid; i < NCODE; i += 256) {
    float c  = (float)histI[i];
    float ns = 0.995f * clusterSize[i] + OMD * c;
    out[OFF_SIZE + i] = ns;
    ln += ns;
    if (ns >= 0.99f) lu += 1.0f;
    float pr = c * (1.0f / 32768.0f);
    le += pr * logf(pr + 1e-5f);
  }
  #pragma unroll
  for (int off = 32; off >= 1; off >>= 1) {
    ln += __shfl_xor(ln, off, 64);
    lu += __shfl_xor(lu, off, 64);
    le += __shfl_xor(le, off, 64);
  }
  __shared__ float sn[4], su[4], se[4];
  int w = tid >> 6;
  if ((tid & 63) == 0) { sn[w] = ln; su[w] = lu; se[w] = le; }
  __syncthreads();
  if (tid == 0) {
    float n = (sn[0] + sn[1]) + (sn[2] + sn[3]);
    float u = (su[0] + su[1]) + (su[2] + su[3]);
    float e = (se[0] + se[1]) + (se[2] + se[3]);
    nOut[0] = n;
    out[OFF_DIFF]  = diffSum[0] * (1.0f / 16777216.0f);
    out[OFF_AVGU]  = u * (1.0f / 4096.0f);
    out[OFF_USAGE] = u;
    out[OFF_ENT]   = -e;
  }
}

// scatter token ids into code-sorted order
__global__ void k_scatter(const int* __restrict__ idxArr, int* __restrict__ cursor,
                          int* __restrict__ sorted) {
  int t = blockIdx.x * blockDim.x + threadIdx.x;
  if (t >= NTOK) return;
  int p = atomicAdd(cursor + idxArr[t], 1);
  sorted[p] = t;
}

// one block per code: raw csum + EMA + embedding in one pass
__global__ void k_csumfinal(const float* __restrict__ x, const int* __restrict__ offs,
                            const int* __restrict__ histI, const int* __restrict__ sorted,
                            const float* __restrict__ clusterSum, const float* __restrict__ newSize,
                            const float* __restrict__ nPtr, float* __restrict__ sumOut,
                            float* __restrict__ embOut) {
  __shared__ int sidx[1024];
  int c   = blockIdx.x;
  int tid = threadIdx.x;
  int o = offs[c], n = histI[c];
  float a0 = 0.0f, a1 = 0.0f;
  for (int base = 0; base < n; base += 1024) {
    int m = min(n - base, 1024);
    __syncthreads();
    for (int j = tid; j < m; j += 256) sidx[j] = sorted[o + base + j];
    __syncthreads();
    for (int j = 0; j < m; j++) {
      const float* xr = x + (size_t)sidx[j] * NDIM;
      a0 += xr[tid];
      a1 += xr[tid + 256];
    }
  }
  const float OMD = (float)(1.0 - 0.995);
  float nv  = nPtr[0];
  float sz  = newSize[c];
  float cnt = (sz + 1e-4f) / (nv + 0.4096f) * nv;
  float rc  = (sz >= 0.99f) ? (1.0f / cnt) : 0.0f;
  size_t i0 = (size_t)c * NDIM + tid;
  size_t i1 = i0 + 256;
  float ns0 = 0.995f * clusterSum[i0] + OMD * a0;
  float ns1 = 0.995f * clusterSum[i1] + OMD * a1;
  sumOut[i0] = ns0;
  sumOut[i1] = ns1;
  embOut[i0] = ns0 * rc;
  embOut[i1] = ns1 * rc;
}

extern "C" void kernel_launch(void* const* d_in, const int* in_sizes, int n_in,
                              void* d_out, int out_size, void* d_ws, size_t ws_size,
                              hipStream_t stream) {
  const float* x   = (const float*)d_in[0];
  const float* emb = (const float*)d_in[1];
  const float* csz = (const float*)d_in[2];
  const float* csm = (const float*)d_in[3];
  float* out = (float*)d_out;

  float* wsf     = (float*)d_ws;
  float* diffSum = wsf;                      // [0]
  float* nScal   = wsf + 1;                  // [1]
  int*   histI   = (int*)(wsf + 64);         // 4096
  int*   offs    = histI + NCODE;            // 4096
  int*   cursor  = offs + NCODE;             // 4096
  float* e2      = (float*)(cursor + NCODE); // 4096
  int*   idxArr  = (int*)(e2 + NCODE);       // 32768
  int*   sorted  = idxArr + NTOK;            // 32768
  unsigned short* xh = (unsigned short*)(sorted + NTOK);
  unsigned short* xl = xh + (size_t)NTOK * NDIM;
  unsigned short* eh = xl + (size_t)NTOK * NDIM;
  unsigned short* el = eh + (size_t)NCODE * NDIM;

  // panel partials live in the (not-yet-written) z region of d_out: 8 MB of 64 MB
  float* pd1 = out + OFF_Z;
  int*   pi1 = (int*)(pd1 + (size_t)NPANEL * NTOK);
  float* pd2 = (float*)(pi1 + (size_t)NPANEL * NTOK);
  int*   pi2 = (int*)(pd2 + (size_t)NPANEL * NTOK);

  const size_t need = (size_t)((char*)(el + (size_t)NCODE * NDIM) - (char*)d_ws);

  if (ws_size >= need) {
    k_prep<<<9216, 256, 0, stream>>>(x, emb, xh, xl, eh, el, e2, wsf);
    k_argmin_mfma<<<256, 512, 0, stream>>>(xh, xl, eh, el, e2, pd1, pi1, pd2, pi2);
    k_combine_recheck<<<NTOK / 256, 256, 0, stream>>>(pd1, pi1, pd2, pi2, x, emb, idxArr);
  } else {
    k_zero<<<(64 + NCODE + 255) / 256, 256, 0, stream>>>(wsf, 64 + NCODE);
    k_rowsq<<<NCODE / 4, 256, 0, stream>>>(emb, e2, NCODE);
    k_argmin_f32<<<NTOK / BM, 256, 0, stream>>>(x, emb, e2, idxArr);
  }

  k_z<<<NTOK / 4, 256, 0, stream>>>(x, emb, idxArr, out + OFF_Z, diffSum, histI, out + OFF_CODES);
  k_scanstats<<<1, 256, 0, stream>>>(histI, offs, cursor, csz, diffSum, out, nScal);
  k_scatter<<<NTOK / 256, 256, 0, stream>>>(idxArr, cursor, sorted);
  k_csumfinal<<<NCODE, 256, 0, stream>>>(x, offs, histI, sorted, csm, out + OFF_SIZE, nScal,
                                         out + OFF_SUM, out + OFF_EMB);
}

// Round 11
// 1306.812 us; speedup vs baseline: 1.1526x; 1.1526x over previous
//
#include <hip/hip_runtime.h>
#include <math.h>

#define NTOK 32768
#define NDIM 512
#define NCODE 4096
#define NPANEL 16
#define PSZ 256

// output layout (flat f32, reference tuple order)
#define OFF_Z      0
#define OFF_DIFF   16777216
#define OFF_CODES  16777217
#define OFF_EMB    16809985
#define OFF_SIZE   18907137
#define OFF_SUM    18911233
#define OFF_AVGU   21008385
#define OFF_USAGE  21008386
#define OFF_ENT    21008387

#define TAU 0.01f

typedef _Float16 f16x8 __attribute__((ext_vector_type(8)));
typedef float f32x4 __attribute__((ext_vector_type(4)));
typedef unsigned short ushort8 __attribute__((ext_vector_type(8)));
typedef unsigned int u32;

__device__ __forceinline__ void atomAddF(float* p, float v) {
  unsafeAtomicAdd(p, v);
}

__device__ __forceinline__ void gload16(const void* g, void* l) {
  __builtin_amdgcn_global_load_lds((const __attribute__((address_space(1))) u32*)g,
                                   (__attribute__((address_space(3))) u32*)l, 16, 0, 0);
}

// involutive 16B-chunk swizzle: bits0-2 ^= bits3-5
__device__ __forceinline__ int swz16(int c) { return c ^ ((c >> 3) & 7); }

// merge other top-2 pair into (d1,i1,d2,i2); index tiebreak = lower wins
__device__ __forceinline__ void mergePair(float& d1, int& i1, float& d2, int& i2,
                                          float od1, int oi1, float od2, int oi2) {
  bool oF = (od1 < d1) || (od1 == d1 && oi1 < i1);
  float w1 = oF ? od1 : d1;  int wi1 = oF ? oi1 : i1;
  float l1 = oF ? d1 : od1;  int li1 = oF ? i1 : oi1;
  bool c = (od2 < d2) || (od2 == d2 && oi2 < i2);
  float c2 = c ? od2 : d2;   int ci2 = c ? oi2 : i2;
  bool lb = (l1 < c2) || (l1 == c2 && li1 < ci2);
  d2 = lb ? l1 : c2; i2 = lb ? li1 : ci2;
  d1 = w1; i1 = wi1;
}

__global__ void k_zero(float* __restrict__ p, int n) {
  int i = blockIdx.x * blockDim.x + threadIdx.x;
  if (i < n) p[i] = 0.0f;
}

// fused prep: blocks [0,8192) split x; blocks [8192,9216) do emb rowsq+split (+ws zero)
__global__ void k_prep(const float* __restrict__ x, const float* __restrict__ emb,
                       unsigned short* __restrict__ xh, unsigned short* __restrict__ xl,
                       unsigned short* __restrict__ eh, unsigned short* __restrict__ el,
                       float* __restrict__ e2, float* __restrict__ wsZero) {
  int b = blockIdx.x, tid = threadIdx.x;
  if (b < 8192) {
    int i = b * 256 + tid;
    const float4* p = (const float4*)(x + (size_t)i * 8);
    float4 a = p[0], bb = p[1];
    float v[8] = {a.x, a.y, a.z, a.w, bb.x, bb.y, bb.z, bb.w};
    ushort8 h, lw;
    #pragma unroll
    for (int j = 0; j < 8; j++) {
      float f = v[j];
      _Float16 hb = (_Float16)f;
      float hf = (float)hb;
      _Float16 lb = (_Float16)(f - hf);
      h[j]  = __builtin_bit_cast(unsigned short, hb);
      lw[j] = __builtin_bit_cast(unsigned short, lb);
    }
    *(ushort8*)(xh + (size_t)i * 8) = h;
    *(ushort8*)(xl + (size_t)i * 8) = lw;
    return;
  }
  int be = b - 8192;
  if (be < 17) {
    int i = be * 256 + tid;
    if (i < 4160) wsZero[i] = 0.0f;
  }
  int w    = tid >> 6;
  int lane = tid & 63;
  int row  = be * 4 + w;
  const float* r = emb + (size_t)row * NDIM + lane * 8;
  float4 a = *(const float4*)r;
  float4 bb = *(const float4*)(r + 4);
  float v[8] = {a.x, a.y, a.z, a.w, bb.x, bb.y, bb.z, bb.w};
  ushort8 h, lw;
  float sq = 0.0f;
  #pragma unroll
  for (int j = 0; j < 8; j++) {
    float f = v[j];
    sq += f * f;
    _Float16 hb = (_Float16)f;
    float hf = (float)hb;
    _Float16 lb = (_Float16)(f - hf);
    h[j]  = __builtin_bit_cast(unsigned short, hb);
    lw[j] = __builtin_bit_cast(unsigned short, lb);
  }
  size_t o = (size_t)row * NDIM + lane * 8;
  *(ushort8*)(eh + o) = h;
  *(ushort8*)(el + o) = lw;
  #pragma unroll
  for (int off = 32; off >= 1; off >>= 1) sq += __shfl_xor(sq, off, 64);
  if (lane == 0) e2[row] = sq;
}

// one wave per row: sum of squares (fallback path only)
__global__ void k_rowsq(const float* __restrict__ rows, float* __restrict__ out, int nrows) {
  int gw   = (blockIdx.x * blockDim.x + threadIdx.x) >> 6;
  int lane = threadIdx.x & 63;
  if (gw >= nrows) return;
  const float* r = rows + (size_t)gw * NDIM + lane * 8;
  float4 a = *(const float4*)r;
  float4 b = *(const float4*)(r + 4);
  float s = ((a.x*a.x + a.y*a.y) + (a.z*a.z + a.w*a.w))
          + ((b.x*b.x + b.y*b.y) + (b.z*b.z + b.w*b.w));
  #pragma unroll
  for (int off = 32; off >= 1; off >>= 1) s += __shfl_xor(s, off, 64);
  if (lane == 0) out[gw] = s;
}

// ===================== MFMA argmin (r7 configuration — measured 456 us) =====================
// grid 256: p = hw&15 (fixed 256-code panel), s = hw>>4 (2048-token subrange, 8 chunks of 256).
// 8 waves: wm 0..3 (64 token rows) x wn 0..1 (128 code cols). acc tile 256x256 per chunk.
// dist = e2 - 2*dot; dot = hh + hl + lh (3 f16 MFMAs). Per-chunk top-2 flush to panel partials.
#define SLOT 8192   // ushorts per LDS buffer (256 rows x 32 k)
__launch_bounds__(512, 2)
__global__ void k_argmin_mfma(const unsigned short* __restrict__ xh, const unsigned short* __restrict__ xl,
                              const unsigned short* __restrict__ eh, const unsigned short* __restrict__ el,
                              const float* __restrict__ e2,
                              float* __restrict__ pd1, int* __restrict__ pi1,
                              float* __restrict__ pd2, int* __restrict__ pi2) {
  __shared__ __align__(16) unsigned short Ah[2 * SLOT];
  __shared__ __align__(16) unsigned short Al[2 * SLOT];
  __shared__ __align__(16) unsigned short Bh[2 * SLOT];
  __shared__ __align__(16) unsigned short Bl[2 * SLOT];
  __shared__ float redD1[512];
  __shared__ int   redI1[512];
  __shared__ float redD2[512];
  __shared__ int   redI2[512];

  const int tid = threadIdx.x;
  const int w   = tid >> 6;
  const int l   = tid & 63;
  const int wm  = w >> 1;     // 0..3: 64-row token group
  const int wn  = w & 1;      // 0..1: 128-col code group
  const int l15 = l & 15;
  const int l4  = l >> 4;

  const int p      = blockIdx.x & 15;
  const int s      = blockIdx.x >> 4;
  const int cbase  = p * PSZ;
  const int tbase0 = s * 2048;

  // fragment LDS offsets (ushort units), swizzled
  int aOff[4], bOff[8];
  #pragma unroll
  for (int mi = 0; mi < 4; mi++) aOff[mi] = swz16(((wm * 64 + mi * 16 + l15) << 2) | l4) * 8;
  #pragma unroll
  for (int nj = 0; nj < 8; nj++) bOff[nj] = swz16(((wn * 128 + nj * 16 + l15) << 2) | l4) * 8;

  // hoisted e2 values (code cols fixed per block)
  float ev[8];
  #pragma unroll
  for (int nj = 0; nj < 8; nj++) ev[nj] = e2[cbase + wn * 128 + nj * 16 + l15];

  // staging: linear LDS chunks {tid, tid+512}; swizzled (row,seg) source (involution)
  int sR[2], sS[2];
  #pragma unroll
  for (int q = 0; q < 2; q++) {
    int sc = swz16(tid + q * 512);
    sR[q] = sc >> 2; sS[q] = (sc & 3) * 8;
  }

  auto STAGE = [&](int buf, int tbase, int k0) {
    #pragma unroll
    for (int q = 0; q < 2; q++) {
      int dst = (tid + q * 512) * 8;
      size_t aGq = (size_t)(tbase + sR[q]) * NDIM + k0 + sS[q];
      gload16(xh + aGq, Ah + buf * SLOT + dst);
      gload16(xl + aGq, Al + buf * SLOT + dst);
      size_t bGq = (size_t)(cbase + sR[q]) * NDIM + k0 + sS[q];
      gload16(eh + bGq, Bh + buf * SLOT + dst);
      gload16(el + bGq, Bl + buf * SLOT + dst);
    }
  };

  STAGE(0, tbase0, 0);
  int cur = 0;
  __syncthreads();

  for (int ci = 0; ci < 8; ci++) {
    const int tbase = tbase0 + ci * 256;
    f32x4 acc[4][8];
    #pragma unroll
    for (int mi = 0; mi < 4; mi++)
      #pragma unroll
      for (int nj = 0; nj < 8; nj++) acc[mi][nj] = (f32x4)0.0f;

    for (int kt = 0; kt < 16; kt++) {
      if (kt < 15)     STAGE(cur ^ 1, tbase, (kt + 1) * 32);
      else if (ci < 7) STAGE(cur ^ 1, tbase + 256, 0);

      const unsigned short* AhC = Ah + cur * SLOT;
      const unsigned short* AlC = Al + cur * SLOT;
      const unsigned short* BhC = Bh + cur * SLOT;
      const unsigned short* BlC = Bl + cur * SLOT;

      f16x8 ah[4], al[4];
      #pragma unroll
      for (int mi = 0; mi < 4; mi++) {
        ah[mi] = *(const f16x8*)(const void*)(AhC + aOff[mi]);
        al[mi] = *(const f16x8*)(const void*)(AlC + aOff[mi]);
      }
      #pragma unroll
      for (int nj = 0; nj < 8; nj++) {
        f16x8 bh = *(const f16x8*)(const void*)(BhC + bOff[nj]);
        f16x8 bl = *(const f16x8*)(const void*)(BlC + bOff[nj]);
        #pragma unroll
        for (int mi = 0; mi < 4; mi++) {
          acc[mi][nj] = __builtin_amdgcn_mfma_f32_16x16x32_f16(ah[mi], bh, acc[mi][nj], 0, 0, 0);
          acc[mi][nj] = __builtin_amdgcn_mfma_f32_16x16x32_f16(ah[mi], bl, acc[mi][nj], 0, 0, 0);
          acc[mi][nj] = __builtin_amdgcn_mfma_f32_16x16x32_f16(al[mi], bh, acc[mi][nj], 0, 0, 0);
        }
      }
      __syncthreads();
      cur ^= 1;
    }

    // per-chunk top-2 over this block's 256-code panel
    float d1[16], d2[16];
    int   i1[16], i2[16];
    #pragma unroll
    for (int t = 0; t < 16; t++) { d1[t] = 1e30f; d2[t] = 1e30f; i1[t] = 0; i2[t] = 0; }
    #pragma unroll
    for (int nj = 0; nj < 8; nj++) {
      int col = cbase + wn * 128 + nj * 16 + l15;
      #pragma unroll
      for (int mi = 0; mi < 4; mi++) {
        #pragma unroll
        for (int r = 0; r < 4; r++) {
          float d = ev[nj] - 2.0f * acc[mi][nj][r];
          int t = mi * 4 + r;
          if (d < d1[t]) { d2[t] = d1[t]; i2[t] = i1[t]; d1[t] = d; i1[t] = col; }
          else if (d < d2[t]) { d2[t] = d; i2[t] = col; }
        }
      }
    }
    // butterfly over the 16 column-lanes
    #pragma unroll
    for (int off = 8; off >= 1; off >>= 1) {
      #pragma unroll
      for (int t = 0; t < 16; t++) {
        float od1 = __shfl_xor(d1[t], off, 16);
        int   oi1 = __shfl_xor(i1[t], off, 16);
        float od2 = __shfl_xor(d2[t], off, 16);
        int   oi2 = __shfl_xor(i2[t], off, 16);
        mergePair(d1[t], i1[t], d2[t], i2[t], od1, oi1, od2, oi2);
      }
    }
    if (l15 == 0) {
      #pragma unroll
      for (int t = 0; t < 16; t++) {
        int rowLocal = wm * 64 + (t >> 2) * 16 + l4 * 4 + (t & 3);
        redD1[wn * 256 + rowLocal] = d1[t];
        redI1[wn * 256 + rowLocal] = i1[t];
        redD2[wn * 256 + rowLocal] = d2[t];
        redI2[wn * 256 + rowLocal] = i2[t];
      }
    }
    __syncthreads();
    if (tid < 256) {
      float a1 = redD1[tid], a2 = redD2[tid];
      int   x1 = redI1[tid], x2 = redI2[tid];
      mergePair(a1, x1, a2, x2, redD1[256 + tid], redI1[256 + tid], redD2[256 + tid], redI2[256 + tid]);
      size_t o = (size_t)p * NTOK + tbase + tid;
      pd1[o] = a1; pi1[o] = x1; pd2[o] = a2; pi2[o] = x2;
    }
  }
}

// merge the 16 panel partials -> idxArr; pair-recheck flagged tokens in-block (f64)
__global__ void k_combine_recheck(const float* __restrict__ pd1, const int* __restrict__ pi1,
                                  const float* __restrict__ pd2, const int* __restrict__ pi2,
                                  const float* __restrict__ x, const float* __restrict__ emb,
                                  int* __restrict__ idxArr) {
  __shared__ int fT[256], fC1[256], fC2[256];
  __shared__ int fcnt;
  int tid = threadIdx.x;
  int t   = blockIdx.x * 256 + tid;
  if (tid == 0) fcnt = 0;
  __syncthreads();

  float a1 = pd1[t], a2 = pd2[t];
  int   x1 = pi1[t], x2 = pi2[t];
  #pragma unroll
  for (int k = 1; k < NPANEL; k++) {
    size_t o = (size_t)k * NTOK + t;
    mergePair(a1, x1, a2, x2, pd1[o], pi1[o], pd2[o], pi2[o]);
  }
  idxArr[t] = x1;
  if (a2 - a1 < TAU) {
    int slot = atomicAdd(&fcnt, 1);
    fT[slot] = t; fC1[slot] = x1; fC2[slot] = x2;
  }
  __syncthreads();

  int n  = fcnt;
  int wv = tid >> 6, lane = tid & 63;
  for (int ti = wv; ti < n; ti += 4) {
    int tt = fT[ti], c1 = fC1[ti], c2 = fC2[ti];
    const float* xr = x   + (size_t)tt * NDIM + lane * 8;
    const float* e1 = emb + (size_t)c1 * NDIM + lane * 8;
    const float* e2 = emb + (size_t)c2 * NDIM + lane * 8;
    double s1 = 0.0, s2 = 0.0;
    #pragma unroll
    for (int j = 0; j < 8; j++) {
      double xv = (double)xr[j];
      double a = (double)e1[j];
      double b = (double)e2[j];
      s1 += a * (a - 2.0 * xv);
      s2 += b * (b - 2.0 * xv);
    }
    #pragma unroll
    for (int off = 32; off >= 1; off >>= 1) {
      s1 += __shfl_xor(s1, off, 64);
      s2 += __shfl_xor(s2, off, 64);
    }
    if (lane == 0) {
      bool take2 = (s2 < s1) || (s2 == s1 && c2 < c1);
      if (take2) idxArr[tt] = c2;
    }
  }
}

// ===================== fallback f32 argmin (small-ws path) =====================
#define BM 64
#define BN 64
#define BK 32
__launch_bounds__(256)
__global__ void k_argmin_f32(const float* __restrict__ x, const float* __restrict__ emb,
                             const float* __restrict__ e2, int* __restrict__ idxOut) {
  __shared__ __align__(16) float xs[BK][BM + 4];
  __shared__ __align__(16) float es[BK][BN + 4];
  const int tid  = threadIdx.x;
  const int tx   = tid & 15;
  const int ty   = tid >> 4;
  const int brow = blockIdx.x * BM;
  const int lk   = tid & 7;
  const int lr   = tid >> 3;

  double best[4];
  int    bidx[4];
  #pragma unroll
  for (int i = 0; i < 4; i++) { best[i] = 1e300; bidx[i] = 0; }

  for (int c0 = 0; c0 < NCODE; c0 += BN) {
    float acc[4][4];
    #pragma unroll
    for (int i = 0; i < 4; i++)
      #pragma unroll
      for (int j = 0; j < 4; j++) acc[i][j] = 0.0f;
    for (int k0 = 0; k0 < NDIM; k0 += BK) {
      __syncthreads();
      float4 v0 = *(const float4*)&x  [(size_t)(brow + lr)      * NDIM + k0 + lk * 4];
      float4 v1 = *(const float4*)&x  [(size_t)(brow + lr + 32) * NDIM + k0 + lk * 4];
      float4 w0 = *(const float4*)&emb[(size_t)(c0   + lr)      * NDIM + k0 + lk * 4];
      float4 w1 = *(const float4*)&emb[(size_t)(c0   + lr + 32) * NDIM + k0 + lk * 4];
      float a0[4] = {v0.x, v0.y, v0.z, v0.w};
      float a1[4] = {v1.x, v1.y, v1.z, v1.w};
      float b0[4] = {w0.x, w0.y, w0.z, w0.w};
      float b1f[4] = {w1.x, w1.y, w1.z, w1.w};
      #pragma unroll
      for (int j = 0; j < 4; j++) {
        xs[lk * 4 + j][lr]      = a0[j];
        xs[lk * 4 + j][lr + 32] = a1[j];
        es[lk * 4 + j][lr]      = b0[j];
        es[lk * 4 + j][lr + 32] = b1f[j];
      }
      __syncthreads();
      #pragma unroll
      for (int k = 0; k < BK; k++) {
        const float4 av = *(const float4*)&xs[k][ty * 4];
        const float4 bv = *(const float4*)&es[k][tx * 4];
        const float ax[4] = {av.x, av.y, av.z, av.w};
        const float bx[4] = {bv.x, bv.y, bv.z, bv.w};
        #pragma unroll
        for (int i = 0; i < 4; i++)
          #pragma unroll
          for (int j = 0; j < 4; j++) acc[i][j] += ax[i] * bx[j];
      }
    }
    #pragma unroll
    for (int j = 0; j < 4; j++) {
      float e2v = e2[c0 + tx * 4 + j];
      int   ci  = c0 + tx * 4 + j;
      #pragma unroll
      for (int i = 0; i < 4; i++) {
        double d = (double)e2v - 2.0 * (double)acc[i][j];
        if (d < best[i]) { best[i] = d; bidx[i] = ci; }
      }
    }
  }
  #pragma unroll
  for (int off = 8; off >= 1; off >>= 1) {
    #pragma unroll
    for (int i = 0; i < 4; i++) {
      double ob = __shfl_xor(best[i], off, 16);
      int    oi = __shfl_xor(bidx[i], off, 16);
      if (ob < best[i] || (ob == best[i] && oi < bidx[i])) { best[i] = ob; bidx[i] = oi; }
    }
  }
  if (tx == 0) {
    #pragma unroll
    for (int i = 0; i < 4; i++) idxOut[brow + ty * 4 + i] = bidx[i];
  }
}

// one wave per token: z, diff partial, int histogram, codes
__global__ void k_z(const float* __restrict__ x, const float* __restrict__ emb,
                    const int* __restrict__ idxArr, float* __restrict__ z,
                    float* __restrict__ diffSum, int* __restrict__ histI,
                    float* __restrict__ codesOut) {
  int t    = (blockIdx.x * blockDim.x + threadIdx.x) >> 6;
  int lane = threadIdx.x & 63;
  if (t >= NTOK) return;
  int idx = idxArr[t];
  const float* xr = x   + (size_t)t   * NDIM;
  const float* er = emb + (size_t)idx * NDIM;
  float* zr = z + (size_t)t * NDIM;
  float part = 0.0f;
  #pragma unroll
  for (int b = 0; b < 2; b++) {
    int k = lane * 8 + b * 4;
    float4 q  = *(const float4*)(er + k);
    float4 xv = *(const float4*)(xr + k);
    float4 dv; dv.x = q.x - xv.x; dv.y = q.y - xv.y; dv.z = q.z - xv.z; dv.w = q.w - xv.w;
    float4 zv; zv.x = xv.x + dv.x; zv.y = xv.y + dv.y; zv.z = xv.z + dv.z; zv.w = xv.w + dv.w;
    *(float4*)(zr + k) = zv;
    part += ((dv.x*dv.x + dv.y*dv.y) + (dv.z*dv.z + dv.w*dv.w));
  }
  #pragma unroll
  for (int off = 32; off >= 1; off >>= 1) part += __shfl_xor(part, off, 64);
  if (lane == 0) {
    atomAddF(diffSum, part);
    atomicAdd(histI + idx, 1);
    codesOut[t] = (float)idx;
  }
}

// single block: prefix-scan over hist + new_size/scalars
__global__ void k_scanstats(const int* __restrict__ histI, int* __restrict__ offs,
                            int* __restrict__ cursor, const float* __restrict__ clusterSize,
                            const float* __restrict__ diffSum, float* __restrict__ out,
                            float* __restrict__ nOut) {
  __shared__ int part[256];
  int tid = threadIdx.x;
  int base = tid * 16;
  int local[16];
  int s = 0;
  #pragma unroll
  for (int j = 0; j < 16; j++) { local[j] = s; s += histI[base + j]; }
  part[tid] = s;
  __syncthreads();
  for (int off = 1; off < 256; off <<= 1) {
    int v = 0;
    if (tid >= off) v = part[tid - off];
    __syncthreads();
    part[tid] += v;
    __syncthreads();
  }
  int pre = (tid == 0) ? 0 : part[tid - 1];
  #pragma unroll
  for (int j = 0; j < 16; j++) {
    int o = pre + local[j];
    offs[base + j]   = o;
    cursor[base + j] = o;
  }

  const float OMD = (float)(1.0 - 0.995);
  float ln = 0.0f, lu = 0.0f, le = 0.0f;
  for (int i = tid; i < NCODE; i += 256) {
    float c  = (float)histI[i];
    float ns = 0.995f * clusterSize[i] + OMD * c;
    out[OFF_SIZE + i] = ns;
    ln += ns;
    if (ns >= 0.99f) lu += 1.0f;
    float pr = c * (1.0f / 32768.0f);
    le += pr * logf(pr + 1e-5f);
  }
  #pragma unroll
  for (int off = 32; off >= 1; off >>= 1) {
    ln += __shfl_xor(ln, off, 64);
    lu += __shfl_xor(lu, off, 64);
    le += __shfl_xor(le, off, 64);
  }
  __shared__ float sn[4], su[4], se[4];
  int w = tid >> 6;
  if ((tid & 63) == 0) { sn[w] = ln; su[w] = lu; se[w] = le; }
  __syncthreads();
  if (tid == 0) {
    float n = (sn[0] + sn[1]) + (sn[2] + sn[3]);
    float u = (su[0] + su[1]) + (su[2] + su[3]);
    float e = (se[0] + se[1]) + (se[2] + se[3]);
    nOut[0] = n;
    out[OFF_DIFF]  = diffSum[0] * (1.0f / 16777216.0f);
    out[OFF_AVGU]  = u * (1.0f / 4096.0f);
    out[OFF_USAGE] = u;
    out[OFF_ENT]   = -e;
  }
}

// scatter token ids into code-sorted order
__global__ void k_scatter(const int* __restrict__ idxArr, int* __restrict__ cursor,
                          int* __restrict__ sorted) {
  int t = blockIdx.x * blockDim.x + threadIdx.x;
  if (t >= NTOK) return;
  int p = atomicAdd(cursor + idxArr[t], 1);
  sorted[p] = t;
}

// one block per code: raw csum + EMA + embedding in one pass
__global__ void k_csumfinal(const float* __restrict__ x, const int* __restrict__ offs,
                            const int* __restrict__ histI, const int* __restrict__ sorted,
                            const float* __restrict__ clusterSum, const float* __restrict__ newSize,
                            const float* __restrict__ nPtr, float* __restrict__ sumOut,
                            float* __restrict__ embOut) {
  __shared__ int sidx[1024];
  int c   = blockIdx.x;
  int tid = threadIdx.x;
  int o = offs[c], n = histI[c];
  float a0 = 0.0f, a1 = 0.0f;
  for (int base = 0; base < n; base += 1024) {
    int m = min(n - base, 1024);
    __syncthreads();
    for (int j = tid; j < m; j += 256) sidx[j] = sorted[o + base + j];
    __syncthreads();
    for (int j = 0; j < m; j++) {
      const float* xr = x + (size_t)sidx[j] * NDIM;
      a0 += xr[tid];
      a1 += xr[tid + 256];
    }
  }
  const float OMD = (float)(1.0 - 0.995);
  float nv  = nPtr[0];
  float sz  = newSize[c];
  float cnt = (sz + 1e-4f) / (nv + 0.4096f) * nv;
  float rc  = (sz >= 0.99f) ? (1.0f / cnt) : 0.0f;
  size_t i0 = (size_t)c * NDIM + tid;
  size_t i1 = i0 + 256;
  float ns0 = 0.995f * clusterSum[i0] + OMD * a0;
  float ns1 = 0.995f * clusterSum[i1] + OMD * a1;
  sumOut[i0] = ns0;
  sumOut[i1] = ns1;
  embOut[i0] = ns0 * rc;
  embOut[i1] = ns1 * rc;
}

extern "C" void kernel_launch(void* const* d_in, const int* in_sizes, int n_in,
                              void* d_out, int out_size, void* d_ws, size_t ws_size,
                              hipStream_t stream) {
  const float* x   = (const float*)d_in[0];
  const float* emb = (const float*)d_in[1];
  const float* csz = (const float*)d_in[2];
  const float* csm = (const float*)d_in[3];
  float* out = (float*)d_out;

  float* wsf     = (float*)d_ws;
  float* diffSum = wsf;                      // [0]
  float* nScal   = wsf + 1;                  // [1]
  int*   histI   = (int*)(wsf + 64);         // 4096
  int*   offs    = histI + NCODE;            // 4096
  int*   cursor  = offs + NCODE;             // 4096
  float* e2      = (float*)(cursor + NCODE); // 4096
  int*   idxArr  = (int*)(e2 + NCODE);       // 32768
  int*   sorted  = idxArr + NTOK;            // 32768
  unsigned short* xh = (unsigned short*)(sorted + NTOK);
  unsigned short* xl = xh + (size_t)NTOK * NDIM;
  unsigned short* eh = xl + (size_t)NTOK * NDIM;
  unsigned short* el = eh + (size_t)NCODE * NDIM;

  // panel partials live in the (not-yet-written) z region of d_out: 8 MB of 64 MB
  float* pd1 = out + OFF_Z;
  int*   pi1 = (int*)(pd1 + (size_t)NPANEL * NTOK);
  float* pd2 = (float*)(pi1 + (size_t)NPANEL * NTOK);
  int*   pi2 = (int*)(pd2 + (size_t)NPANEL * NTOK);

  const size_t need = (size_t)((char*)(el + (size_t)NCODE * NDIM) - (char*)d_ws);

  if (ws_size >= need) {
    k_prep<<<9216, 256, 0, stream>>>(x, emb, xh, xl, eh, el, e2, wsf);
    k_argmin_mfma<<<256, 512, 0, stream>>>(xh, xl, eh, el, e2, pd1, pi1, pd2, pi2);
    k_combine_recheck<<<NTOK / 256, 256, 0, stream>>>(pd1, pi1, pd2, pi2, x, emb, idxArr);
  } else {
    k_zero<<<(64 + NCODE + 255) / 256, 256, 0, stream>>>(wsf, 64 + NCODE);
    k_rowsq<<<NCODE / 4, 256, 0, stream>>>(emb, e2, NCODE);
    k_argmin_f32<<<NTOK / BM, 256, 0, stream>>>(x, emb, e2, idxArr);
  }

  k_z<<<NTOK / 4, 256, 0, stream>>>(x, emb, idxArr, out + OFF_Z, diffSum, histI, out + OFF_CODES);
  k_scanstats<<<1, 256, 0, stream>>>(histI, offs, cursor, csz, diffSum, out, nScal);
  k_scatter<<<NTOK / 256, 256, 0, stream>>>(idxArr, cursor, sorted);
  k_csumfinal<<<NCODE, 256, 0, stream>>>(x, offs, histI, sorted, csm, out + OFF_SIZE, nScal,
                                         out + OFF_SUM, out + OFF_EMB);
}

// Round 12
// 940.629 us; speedup vs baseline: 1.6013x; 1.3893x over previous
//
#include <hip/hip_runtime.h>
#include <math.h>

#define NTOK 32768
#define NDIM 512
#define NCODE 4096

// output layout (flat f32, reference tuple order)
#define OFF_Z      0
#define OFF_DIFF   16777216
#define OFF_CODES  16777217
#define OFF_EMB    16809985
#define OFF_SIZE   18907137
#define OFF_SUM    18911233
#define OFF_AVGU   21008385
#define OFF_USAGE  21008386
#define OFF_ENT    21008387

#define TAU 0.01f

typedef _Float16 f16x8 __attribute__((ext_vector_type(8)));
typedef float f32x4 __attribute__((ext_vector_type(4)));
typedef unsigned short ushort8 __attribute__((ext_vector_type(8)));
typedef unsigned int u32;

__device__ __forceinline__ void atomAddF(float* p, float v) {
  unsafeAtomicAdd(p, v);
}

__device__ __forceinline__ void gload16(const void* g, void* l) {
  __builtin_amdgcn_global_load_lds((const __attribute__((address_space(1))) u32*)g,
                                   (__attribute__((address_space(3))) u32*)l, 16, 0, 0);
}

// involutive 16B-chunk swizzle: bits0-2 ^= bits3-5
__device__ __forceinline__ int swz16(int c) { return c ^ ((c >> 3) & 7); }

// merge other top-2 pair into (d1,i1,d2,i2); index tiebreak = lower wins
__device__ __forceinline__ void mergePair(float& d1, int& i1, float& d2, int& i2,
                                          float od1, int oi1, float od2, int oi2) {
  bool oF = (od1 < d1) || (od1 == d1 && oi1 < i1);
  float w1 = oF ? od1 : d1;  int wi1 = oF ? oi1 : i1;
  float l1 = oF ? d1 : od1;  int li1 = oF ? i1 : oi1;
  bool c = (od2 < d2) || (od2 == d2 && oi2 < i2);
  float c2 = c ? od2 : d2;   int ci2 = c ? oi2 : i2;
  bool lb = (l1 < c2) || (l1 == c2 && li1 < ci2);
  d2 = lb ? l1 : c2; i2 = lb ? li1 : ci2;
  d1 = w1; i1 = wi1;
}

__global__ void k_zero(float* __restrict__ p, int n) {
  int i = blockIdx.x * blockDim.x + threadIdx.x;
  if (i < n) p[i] = 0.0f;
}

// fused prep: blocks [0,8192) split x; blocks [8192,9216) do emb rowsq+split (+ws zero)
__global__ void k_prep(const float* __restrict__ x, const float* __restrict__ emb,
                       unsigned short* __restrict__ xh, unsigned short* __restrict__ xl,
                       unsigned short* __restrict__ eh, unsigned short* __restrict__ el,
                       float* __restrict__ e2, float* __restrict__ wsZero) {
  int b = blockIdx.x, tid = threadIdx.x;
  if (b < 8192) {
    int i = b * 256 + tid;
    const float4* p = (const float4*)(x + (size_t)i * 8);
    float4 a = p[0], bb = p[1];
    float v[8] = {a.x, a.y, a.z, a.w, bb.x, bb.y, bb.z, bb.w};
    ushort8 h, lw;
    #pragma unroll
    for (int j = 0; j < 8; j++) {
      float f = v[j];
      _Float16 hb = (_Float16)f;
      float hf = (float)hb;
      _Float16 lb = (_Float16)(f - hf);
      h[j]  = __builtin_bit_cast(unsigned short, hb);
      lw[j] = __builtin_bit_cast(unsigned short, lb);
    }
    *(ushort8*)(xh + (size_t)i * 8) = h;
    *(ushort8*)(xl + (size_t)i * 8) = lw;
    return;
  }
  int be = b - 8192;
  if (be < 17) {
    int i = be * 256 + tid;
    if (i < 4160) wsZero[i] = 0.0f;
  }
  int w    = tid >> 6;
  int lane = tid & 63;
  int row  = be * 4 + w;
  const float* r = emb + (size_t)row * NDIM + lane * 8;
  float4 a = *(const float4*)r;
  float4 bb = *(const float4*)(r + 4);
  float v[8] = {a.x, a.y, a.z, a.w, bb.x, bb.y, bb.z, bb.w};
  ushort8 h, lw;
  float sq = 0.0f;
  #pragma unroll
  for (int j = 0; j < 8; j++) {
    float f = v[j];
    sq += f * f;
    _Float16 hb = (_Float16)f;
    float hf = (float)hb;
    _Float16 lb = (_Float16)(f - hf);
    h[j]  = __builtin_bit_cast(unsigned short, hb);
    lw[j] = __builtin_bit_cast(unsigned short, lb);
  }
  size_t o = (size_t)row * NDIM + lane * 8;
  *(ushort8*)(eh + o) = h;
  *(ushort8*)(el + o) = lw;
  #pragma unroll
  for (int off = 32; off >= 1; off >>= 1) sq += __shfl_xor(sq, off, 64);
  if (lane == 0) e2[row] = sq;
}

// one wave per row: sum of squares (fallback path only)
__global__ void k_rowsq(const float* __restrict__ rows, float* __restrict__ out, int nrows) {
  int gw   = (blockIdx.x * blockDim.x + threadIdx.x) >> 6;
  int lane = threadIdx.x & 63;
  if (gw >= nrows) return;
  const float* r = rows + (size_t)gw * NDIM + lane * 8;
  float4 a = *(const float4*)r;
  float4 b = *(const float4*)(r + 4);
  float s = ((a.x*a.x + a.y*a.y) + (a.z*a.z + a.w*a.w))
          + ((b.x*b.x + b.y*b.y) + (b.z*b.z + b.w*b.w));
  #pragma unroll
  for (int off = 32; off >= 1; off >>= 1) s += __shfl_xor(s, off, 64);
  if (lane == 0) out[gw] = s;
}

// ===================== MFMA argmin (round-6 configuration — measured 456 us) =====================
// grid 256 = 128 token-panels (BM=256) x 2 code-halves (2048 each).
// XCD-partitioned: half = (h>>2)&1, panel = (h>>3)*4 + (h&3).
// Block sweeps its half in 8 chunks of 256 codes; acc tile 256x256; 8 waves (wm4 x wn2).
// dist = e2 - 2*dot; dot = hh + hl + lh (3 f16 MFMAs). Single top-2 flush after the half.
#define SLOT 8192   // ushorts per LDS slot (256 rows x 32 k)
__launch_bounds__(512, 2)
__global__ void k_argmin_mfma(const unsigned short* __restrict__ xh, const unsigned short* __restrict__ xl,
                              const unsigned short* __restrict__ eh, const unsigned short* __restrict__ el,
                              const float* __restrict__ e2,
                              float* __restrict__ pd1, int* __restrict__ pi1,
                              float* __restrict__ pd2, int* __restrict__ pi2) {
  __shared__ __align__(16) unsigned short Ah[2 * SLOT];   // 32 KB (reused for reduction)
  __shared__ __align__(16) unsigned short Al[2 * SLOT];
  __shared__ __align__(16) unsigned short Bh[2 * SLOT];
  __shared__ __align__(16) unsigned short Bl[2 * SLOT];

  const int tid = threadIdx.x;
  const int w   = tid >> 6;
  const int l   = tid & 63;
  const int wm  = w >> 1;     // 0..3: 64-row group
  const int wn  = w & 1;      // 0..1: 128-col group
  const int l15 = l & 15;
  const int l4  = l >> 4;

  const int h     = blockIdx.x;
  const int half  = (h >> 2) & 1;
  const int panel = (h >> 3) * 4 + (h & 3);
  const int brow  = panel * 256;
  const int cbase = half * 2048;

  // fragment LDS offsets (ushort units), swizzled
  int aOff[4], bOff[8];
  #pragma unroll
  for (int mi = 0; mi < 4; mi++) aOff[mi] = swz16(((wm * 64 + mi * 16 + l15) << 2) | l4) * 8;
  #pragma unroll
  for (int nj = 0; nj < 8; nj++) bOff[nj] = swz16(((wn * 128 + nj * 16 + l15) << 2) | l4) * 8;

  // staging: linear LDS chunks {tid, tid+512}; swizzled (row,seg) source (involution)
  int sR[2], sS[2];
  #pragma unroll
  for (int q = 0; q < 2; q++) {
    int sc = swz16(tid + q * 512);
    sR[q] = sc >> 2; sS[q] = (sc & 3) * 8;
  }
  size_t aG[2];
  #pragma unroll
  for (int q = 0; q < 2; q++) aG[q] = (size_t)(brow + sR[q]) * NDIM + sS[q];

  float d1[16], d2[16];
  int   i1[16], i2[16];
  #pragma unroll
  for (int s = 0; s < 16; s++) { d1[s] = 1e30f; d2[s] = 1e30f; i1[s] = 0; i2[s] = 0; }

  auto STAGE = [&](int buf, int c0, int k0) {
    #pragma unroll
    for (int q = 0; q < 2; q++) {
      int dst = (tid + q * 512) * 8;
      gload16(xh + aG[q] + k0, Ah + buf * SLOT + dst);
      gload16(xl + aG[q] + k0, Al + buf * SLOT + dst);
      size_t bGq = (size_t)(c0 + sR[q]) * NDIM + k0 + sS[q];
      gload16(eh + bGq, Bh + buf * SLOT + dst);
      gload16(el + bGq, Bl + buf * SLOT + dst);
    }
  };

  STAGE(0, cbase, 0);
  int cur = 0;
  __syncthreads();

  for (int ci = 0; ci < 8; ci++) {
    const int c0 = cbase + ci * 256;
    f32x4 acc[4][8];
    #pragma unroll
    for (int mi = 0; mi < 4; mi++)
      #pragma unroll
      for (int nj = 0; nj < 8; nj++) acc[mi][nj] = (f32x4)0.0f;

    for (int kt = 0; kt < 16; kt++) {
      if (kt < 15)     STAGE(cur ^ 1, c0, (kt + 1) * 32);
      else if (ci < 7) STAGE(cur ^ 1, c0 + 256, 0);

      const unsigned short* AhC = Ah + cur * SLOT;
      const unsigned short* AlC = Al + cur * SLOT;
      const unsigned short* BhC = Bh + cur * SLOT;
      const unsigned short* BlC = Bl + cur * SLOT;

      f16x8 ah[4], al[4];
      #pragma unroll
      for (int mi = 0; mi < 4; mi++) {
        ah[mi] = *(const f16x8*)(const void*)(AhC + aOff[mi]);
        al[mi] = *(const f16x8*)(const void*)(AlC + aOff[mi]);
      }
      #pragma unroll
      for (int nj = 0; nj < 8; nj++) {
        f16x8 bh = *(const f16x8*)(const void*)(BhC + bOff[nj]);
        f16x8 bl = *(const f16x8*)(const void*)(BlC + bOff[nj]);
        #pragma unroll
        for (int mi = 0; mi < 4; mi++) {
          acc[mi][nj] = __builtin_amdgcn_mfma_f32_16x16x32_f16(ah[mi], bh, acc[mi][nj], 0, 0, 0);
          acc[mi][nj] = __builtin_amdgcn_mfma_f32_16x16x32_f16(ah[mi], bl, acc[mi][nj], 0, 0, 0);
          acc[mi][nj] = __builtin_amdgcn_mfma_f32_16x16x32_f16(al[mi], bh, acc[mi][nj], 0, 0, 0);
        }
      }
      __syncthreads();
      cur ^= 1;
    }

    // top-2 update for this 256-code chunk (accumulates across the whole half)
    #pragma unroll
    for (int nj = 0; nj < 8; nj++) {
      int col  = c0 + wn * 128 + nj * 16 + l15;
      float ev = e2[col];
      #pragma unroll
      for (int mi = 0; mi < 4; mi++) {
        #pragma unroll
        for (int r = 0; r < 4; r++) {
          float d = ev - 2.0f * acc[mi][nj][r];
          int s = mi * 4 + r;
          if (d < d1[s]) { d2[s] = d1[s]; i2[s] = i1[s]; d1[s] = d; i1[s] = col; }
          else if (d < d2[s]) { d2[s] = d; i2[s] = col; }
        }
      }
    }
  }

  // butterfly merge across the 16 column-lanes
  #pragma unroll
  for (int off = 8; off >= 1; off >>= 1) {
    #pragma unroll
    for (int s = 0; s < 16; s++) {
      float od1 = __shfl_xor(d1[s], off, 16);
      int   oi1 = __shfl_xor(i1[s], off, 16);
      float od2 = __shfl_xor(d2[s], off, 16);
      int   oi2 = __shfl_xor(i2[s], off, 16);
      mergePair(d1[s], i1[s], d2[s], i2[s], od1, oi1, od2, oi2);
    }
  }

  // reduce across the 2 wn groups via LDS (reuse Ah region: 8 KB of 32 KB)
  float* redD1 = (float*)Ah;           // [2][256]
  int*   redI1 = (int*)Ah + 512;
  float* redD2 = (float*)Ah + 1024;
  int*   redI2 = (int*)Ah + 1536;
  __syncthreads();
  if (l15 == 0) {
    #pragma unroll
    for (int s = 0; s < 16; s++) {
      int rowLocal = wm * 64 + (s >> 2) * 16 + l4 * 4 + (s & 3);
      redD1[wn * 256 + rowLocal] = d1[s];
      redI1[wn * 256 + rowLocal] = i1[s];
      redD2[wn * 256 + rowLocal] = d2[s];
      redI2[wn * 256 + rowLocal] = i2[s];
    }
  }
  __syncthreads();
  if (tid < 256) {
    float a1 = redD1[tid], a2 = redD2[tid];
    int   x1 = redI1[tid], x2 = redI2[tid];
    mergePair(a1, x1, a2, x2, redD1[256 + tid], redI1[256 + tid], redD2[256 + tid], redI2[256 + tid]);
    size_t o = (size_t)half * NTOK + brow + tid;
    pd1[o] = a1; pi1[o] = x1; pd2[o] = a2; pi2[o] = x2;
  }
}

// merge the two code-half partials -> idxArr; pair-recheck flagged tokens in-block (f64)
__global__ void k_combine_recheck(const float* __restrict__ pd1, const int* __restrict__ pi1,
                                  const float* __restrict__ pd2, const int* __restrict__ pi2,
                                  const float* __restrict__ x, const float* __restrict__ emb,
                                  int* __restrict__ idxArr) {
  __shared__ int fT[256], fC1[256], fC2[256];
  __shared__ int fcnt;
  int tid = threadIdx.x;
  int t   = blockIdx.x * 256 + tid;
  if (tid == 0) fcnt = 0;
  __syncthreads();

  float a1 = pd1[t], a2 = pd2[t];
  int   x1 = pi1[t], x2 = pi2[t];
  mergePair(a1, x1, a2, x2, pd1[NTOK + t], pi1[NTOK + t], pd2[NTOK + t], pi2[NTOK + t]);
  idxArr[t] = x1;
  if (a2 - a1 < TAU) {
    int slot = atomicAdd(&fcnt, 1);
    fT[slot] = t; fC1[slot] = x1; fC2[slot] = x2;
  }
  __syncthreads();

  int n  = fcnt;
  int wv = tid >> 6, lane = tid & 63;
  for (int ti = wv; ti < n; ti += 4) {
    int tt = fT[ti], c1 = fC1[ti], c2 = fC2[ti];
    const float* xr = x   + (size_t)tt * NDIM + lane * 8;
    const float* e1 = emb + (size_t)c1 * NDIM + lane * 8;
    const float* e2 = emb + (size_t)c2 * NDIM + lane * 8;
    double s1 = 0.0, s2 = 0.0;
    #pragma unroll
    for (int j = 0; j < 8; j++) {
      double xv = (double)xr[j];
      double a = (double)e1[j];
      double b = (double)e2[j];
      s1 += a * (a - 2.0 * xv);
      s2 += b * (b - 2.0 * xv);
    }
    #pragma unroll
    for (int off = 32; off >= 1; off >>= 1) {
      s1 += __shfl_xor(s1, off, 64);
      s2 += __shfl_xor(s2, off, 64);
    }
    if (lane == 0) {
      bool take2 = (s2 < s1) || (s2 == s1 && c2 < c1);
      if (take2) idxArr[tt] = c2;
    }
  }
}

// ===================== fallback f32 argmin (small-ws path) =====================
#define BM 64
#define BN 64
#define BK 32
__launch_bounds__(256)
__global__ void k_argmin_f32(const float* __restrict__ x, const float* __restrict__ emb,
                             const float* __restrict__ e2, int* __restrict__ idxOut) {
  __shared__ __align__(16) float xs[BK][BM + 4];
  __shared__ __align__(16) float es[BK][BN + 4];
  const int tid  = threadIdx.x;
  const int tx   = tid & 15;
  const int ty   = tid >> 4;
  const int brow = blockIdx.x * BM;
  const int lk   = tid & 7;
  const int lr   = tid >> 3;

  double best[4];
  int    bidx[4];
  #pragma unroll
  for (int i = 0; i < 4; i++) { best[i] = 1e300; bidx[i] = 0; }

  for (int c0 = 0; c0 < NCODE; c0 += BN) {
    float acc[4][4];
    #pragma unroll
    for (int i = 0; i < 4; i++)
      #pragma unroll
      for (int j = 0; j < 4; j++) acc[i][j] = 0.0f;
    for (int k0 = 0; k0 < NDIM; k0 += BK) {
      __syncthreads();
      float4 v0 = *(const float4*)&x  [(size_t)(brow + lr)      * NDIM + k0 + lk * 4];
      float4 v1 = *(const float4*)&x  [(size_t)(brow + lr + 32) * NDIM + k0 + lk * 4];
      float4 w0 = *(const float4*)&emb[(size_t)(c0   + lr)      * NDIM + k0 + lk * 4];
      float4 w1 = *(const float4*)&emb[(size_t)(c0   + lr + 32) * NDIM + k0 + lk * 4];
      float a0[4] = {v0.x, v0.y, v0.z, v0.w};
      float a1[4] = {v1.x, v1.y, v1.z, v1.w};
      float b0[4] = {w0.x, w0.y, w0.z, w0.w};
      float b1f[4] = {w1.x, w1.y, w1.z, w1.w};
      #pragma unroll
      for (int j = 0; j < 4; j++) {
        xs[lk * 4 + j][lr]      = a0[j];
        xs[lk * 4 + j][lr + 32] = a1[j];
        es[lk * 4 + j][lr]      = b0[j];
        es[lk * 4 + j][lr + 32] = b1f[j];
      }
      __syncthreads();
      #pragma unroll
      for (int k = 0; k < BK; k++) {
        const float4 av = *(const float4*)&xs[k][ty * 4];
        const float4 bv = *(const float4*)&es[k][tx * 4];
        const float ax[4] = {av.x, av.y, av.z, av.w};
        const float bx[4] = {bv.x, bv.y, bv.z, bv.w};
        #pragma unroll
        for (int i = 0; i < 4; i++)
          #pragma unroll
          for (int j = 0; j < 4; j++) acc[i][j] += ax[i] * bx[j];
      }
    }
    #pragma unroll
    for (int j = 0; j < 4; j++) {
      float e2v = e2[c0 + tx * 4 + j];
      int   ci  = c0 + tx * 4 + j;
      #pragma unroll
      for (int i = 0; i < 4; i++) {
        double d = (double)e2v - 2.0 * (double)acc[i][j];
        if (d < best[i]) { best[i] = d; bidx[i] = ci; }
      }
    }
  }
  #pragma unroll
  for (int off = 8; off >= 1; off >>= 1) {
    #pragma unroll
    for (int i = 0; i < 4; i++) {
      double ob = __shfl_xor(best[i], off, 16);
      int    oi = __shfl_xor(bidx[i], off, 16);
      if (ob < best[i] || (ob == best[i] && oi < bidx[i])) { best[i] = ob; bidx[i] = oi; }
    }
  }
  if (tx == 0) {
    #pragma unroll
    for (int i = 0; i < 4; i++) idxOut[brow + ty * 4 + i] = bidx[i];
  }
}

// one wave per token: z, diff partial, int histogram, codes
__global__ void k_z(const float* __restrict__ x, const float* __restrict__ emb,
                    const int* __restrict__ idxArr, float* __restrict__ z,
                    float* __restrict__ diffSum, int* __restrict__ histI,
                    float* __restrict__ codesOut) {
  int t    = (blockIdx.x * blockDim.x + threadIdx.x) >> 6;
  int lane = threadIdx.x & 63;
  if (t >= NTOK) return;
  int idx = idxArr[t];
  const float* xr = x   + (size_t)t   * NDIM;
  const float* er = emb + (size_t)idx * NDIM;
  float* zr = z + (size_t)t * NDIM;
  float part = 0.0f;
  #pragma unroll
  for (int b = 0; b < 2; b++) {
    int k = lane * 8 + b * 4;
    float4 q  = *(const float4*)(er + k);
    float4 xv = *(const float4*)(xr + k);
    float4 dv; dv.x = q.x - xv.x; dv.y = q.y - xv.y; dv.z = q.z - xv.z; dv.w = q.w - xv.w;
    float4 zv; zv.x = xv.x + dv.x; zv.y = xv.y + dv.y; zv.z = xv.z + dv.z; zv.w = xv.w + dv.w;
    *(float4*)(zr + k) = zv;
    part += ((dv.x*dv.x + dv.y*dv.y) + (dv.z*dv.z + dv.w*dv.w));
  }
  #pragma unroll
  for (int off = 32; off >= 1; off >>= 1) part += __shfl_xor(part, off, 64);
  if (lane == 0) {
    atomAddF(diffSum, part);
    atomicAdd(histI + idx, 1);
    codesOut[t] = (float)idx;
  }
}

// single block: prefix-scan over hist + new_size/scalars
__global__ void k_scanstats(const int* __restrict__ histI, int* __restrict__ offs,
                            int* __restrict__ cursor, const float* __restrict__ clusterSize,
                            const float* __restrict__ diffSum, float* __restrict__ out,
                            float* __restrict__ nOut) {
  __shared__ int part[256];
  int tid = threadIdx.x;
  int base = tid * 16;
  int local[16];
  int s = 0;
  #pragma unroll
  for (int j = 0; j < 16; j++) { local[j] = s; s += histI[base + j]; }
  part[tid] = s;
  __syncthreads();
  for (int off = 1; off < 256; off <<= 1) {
    int v = 0;
    if (tid >= off) v = part[tid - off];
    __syncthreads();
    part[tid] += v;
    __syncthreads();
  }
  int pre = (tid == 0) ? 0 : part[tid - 1];
  #pragma unroll
  for (int j = 0; j < 16; j++) {
    int o = pre + local[j];
    offs[base + j]   = o;
    cursor[base + j] = o;
  }

  const float OMD = (float)(1.0 - 0.995);
  float ln = 0.0f, lu = 0.0f, le = 0.0f;
  for (int i = tid; i < NCODE; i += 256) {
    float c  = (float)histI[i];
    float ns = 0.995f * clusterSize[i] + OMD * c;
    out[OFF_SIZE + i] = ns;
    ln += ns;
    if (ns >= 0.99f) lu += 1.0f;
    float pr = c * (1.0f / 32768.0f);
    le += pr * logf(pr + 1e-5f);
  }
  #pragma unroll
  for (int off = 32; off >= 1; off >>= 1) {
    ln += __shfl_xor(ln, off, 64);
    lu += __shfl_xor(lu, off, 64);
    le += __shfl_xor(le, off, 64);
  }
  __shared__ float sn[4], su[4], se[4];
  int w = tid >> 6;
  if ((tid & 63) == 0) { sn[w] = ln; su[w] = lu; se[w] = le; }
  __syncthreads();
  if (tid == 0) {
    float n = (sn[0] + sn[1]) + (sn[2] + sn[3]);
    float u = (su[0] + su[1]) + (su[2] + su[3]);
    float e = (se[0] + se[1]) + (se[2] + se[3]);
    nOut[0] = n;
    out[OFF_DIFF]  = diffSum[0] * (1.0f / 16777216.0f);
    out[OFF_AVGU]  = u * (1.0f / 4096.0f);
    out[OFF_USAGE] = u;
    out[OFF_ENT]   = -e;
  }
}

// scatter token ids into code-sorted order
__global__ void k_scatter(const int* __restrict__ idxArr, int* __restrict__ cursor,
                          int* __restrict__ sorted) {
  int t = blockIdx.x * blockDim.x + threadIdx.x;
  if (t >= NTOK) return;
  int p = atomicAdd(cursor + idxArr[t], 1);
  sorted[p] = t;
}

// one block per code: raw csum + EMA + embedding in one pass
__global__ void k_csumfinal(const float* __restrict__ x, const int* __restrict__ offs,
                            const int* __restrict__ histI, const int* __restrict__ sorted,
                            const float* __restrict__ clusterSum, const float* __restrict__ newSize,
                            const float* __restrict__ nPtr, float* __restrict__ sumOut,
                            float* __restrict__ embOut) {
  __shared__ int sidx[1024];
  int c   = blockIdx.x;
  int tid = threadIdx.x;
  int o = offs[c], n = histI[c];
  float a0 = 0.0f, a1 = 0.0f;
  for (int base = 0; base < n; base += 1024) {
    int m = min(n - base, 1024);
    __syncthreads();
    for (int j = tid; j < m; j += 256) sidx[j] = sorted[o + base + j];
    __syncthreads();
    for (int j = 0; j < m; j++) {
      const float* xr = x + (size_t)sidx[j] * NDIM;
      a0 += xr[tid];
      a1 += xr[tid + 256];
    }
  }
  const float OMD = (float)(1.0 - 0.995);
  float nv  = nPtr[0];
  float sz  = newSize[c];
  float cnt = (sz + 1e-4f) / (nv + 0.4096f) * nv;
  float rc  = (sz >= 0.99f) ? (1.0f / cnt) : 0.0f;
  size_t i0 = (size_t)c * NDIM + tid;
  size_t i1 = i0 + 256;
  float ns0 = 0.995f * clusterSum[i0] + OMD * a0;
  float ns1 = 0.995f * clusterSum[i1] + OMD * a1;
  sumOut[i0] = ns0;
  sumOut[i1] = ns1;
  embOut[i0] = ns0 * rc;
  embOut[i1] = ns1 * rc;
}

extern "C" void kernel_launch(void* const* d_in, const int* in_sizes, int n_in,
                              void* d_out, int out_size, void* d_ws, size_t ws_size,
                              hipStream_t stream) {
  const float* x   = (const float*)d_in[0];
  const float* emb = (const float*)d_in[1];
  const float* csz = (const float*)d_in[2];
  const float* csm = (const float*)d_in[3];
  float* out = (float*)d_out;

  float* wsf     = (float*)d_ws;
  float* diffSum = wsf;                      // [0]
  float* nScal   = wsf + 1;                  // [1]
  int*   histI   = (int*)(wsf + 64);         // 4096
  int*   offs    = histI + NCODE;            // 4096
  int*   cursor  = offs + NCODE;             // 4096
  float* e2      = (float*)(cursor + NCODE); // 4096
  int*   idxArr  = (int*)(e2 + NCODE);       // 32768
  int*   sorted  = idxArr + NTOK;            // 32768
  float* pd1     = (float*)(sorted + NTOK);  // 2*32768
  int*   pi1     = (int*)(pd1 + 2 * NTOK);   // 2*32768
  float* pd2     = (float*)(pi1 + 2 * NTOK); // 2*32768
  int*   pi2     = (int*)(pd2 + 2 * NTOK);   // 2*32768
  unsigned short* xh = (unsigned short*)(pi2 + 2 * NTOK);
  unsigned short* xl = xh + (size_t)NTOK * NDIM;
  unsigned short* eh = xl + (size_t)NTOK * NDIM;
  unsigned short* el = eh + (size_t)NCODE * NDIM;

  const size_t need = (size_t)((char*)(el + (size_t)NCODE * NDIM) - (char*)d_ws);

  if (ws_size >= need) {
    k_prep<<<9216, 256, 0, stream>>>(x, emb, xh, xl, eh, el, e2, wsf);
    k_argmin_mfma<<<256, 512, 0, stream>>>(xh, xl, eh, el, e2, pd1, pi1, pd2, pi2);
    k_combine_recheck<<<NTOK / 256, 256, 0, stream>>>(pd1, pi1, pd2, pi2, x, emb, idxArr);
  } else {
    k_zero<<<(64 + NCODE + 255) / 256, 256, 0, stream>>>(wsf, 64 + NCODE);
    k_rowsq<<<NCODE / 4, 256, 0, stream>>>(emb, e2, NCODE);
    k_argmin_f32<<<NTOK / BM, 256, 0, stream>>>(x, emb, e2, idxArr);
  }

  k_z<<<NTOK / 4, 256, 0, stream>>>(x, emb, idxArr, out + OFF_Z, diffSum, histI, out + OFF_CODES);
  k_scanstats<<<1, 256, 0, stream>>>(histI, offs, cursor, csz, diffSum, out, nScal);
  k_scatter<<<NTOK / 256, 256, 0, stream>>>(idxArr, cursor, sorted);
  k_csumfinal<<<NCODE, 256, 0, stream>>>(x, offs, histI, sorted, csm, out + OFF_SIZE, nScal,
                                         out + OFF_SUM, out + OFF_EMB);
}

// Round 13
// 585.768 us; speedup vs baseline: 2.5713x; 1.6058x over previous
//
#include <hip/hip_runtime.h>
#include <math.h>

#define NTOK 32768
#define NDIM 512
#define NCODE 4096

// output layout (flat f32, reference tuple order)
#define OFF_Z      0
#define OFF_DIFF   16777216
#define OFF_CODES  16777217
#define OFF_EMB    16809985
#define OFF_SIZE   18907137
#define OFF_SUM    18911233
#define OFF_AVGU   21008385
#define OFF_USAGE  21008386
#define OFF_ENT    21008387

#define TAU 0.01f

typedef _Float16 f16x8 __attribute__((ext_vector_type(8)));
typedef float f32x4 __attribute__((ext_vector_type(4)));
typedef unsigned short ushort8 __attribute__((ext_vector_type(8)));
typedef unsigned int u32;

__device__ __forceinline__ void atomAddF(float* p, float v) {
  unsafeAtomicAdd(p, v);
}

__device__ __forceinline__ void gload16(const void* g, void* l) {
  __builtin_amdgcn_global_load_lds((const __attribute__((address_space(1))) u32*)g,
                                   (__attribute__((address_space(3))) u32*)l, 16, 0, 0);
}

// involutive 16B-chunk swizzle: bits0-2 ^= bits3-5
__device__ __forceinline__ int swz16(int c) { return c ^ ((c >> 3) & 7); }

// merge other top-2 pair into (d1,i1,d2,i2); index tiebreak = lower wins
__device__ __forceinline__ void mergePair(float& d1, int& i1, float& d2, int& i2,
                                          float od1, int oi1, float od2, int oi2) {
  bool oF = (od1 < d1) || (od1 == d1 && oi1 < i1);
  float w1 = oF ? od1 : d1;  int wi1 = oF ? oi1 : i1;
  float l1 = oF ? d1 : od1;  int li1 = oF ? i1 : oi1;
  bool c = (od2 < d2) || (od2 == d2 && oi2 < i2);
  float c2 = c ? od2 : d2;   int ci2 = c ? oi2 : i2;
  bool lb = (l1 < c2) || (l1 == c2 && li1 < ci2);
  d2 = lb ? l1 : c2; i2 = lb ? li1 : ci2;
  d1 = w1; i1 = wi1;
}

__global__ void k_zero(float* __restrict__ p, int n) {
  int i = blockIdx.x * blockDim.x + threadIdx.x;
  if (i < n) p[i] = 0.0f;
}

// fused prep: blocks [0,8192) split x; blocks [8192,9216) do emb rowsq+split (+ws zero)
__global__ void k_prep(const float* __restrict__ x, const float* __restrict__ emb,
                       unsigned short* __restrict__ xh, unsigned short* __restrict__ xl,
                       unsigned short* __restrict__ eh, unsigned short* __restrict__ el,
                       float* __restrict__ e2, float* __restrict__ wsZero) {
  int b = blockIdx.x, tid = threadIdx.x;
  if (b < 8192) {
    int i = b * 256 + tid;
    const float4* p = (const float4*)(x + (size_t)i * 8);
    float4 a = p[0], bb = p[1];
    float v[8] = {a.x, a.y, a.z, a.w, bb.x, bb.y, bb.z, bb.w};
    ushort8 h, lw;
    #pragma unroll
    for (int j = 0; j < 8; j++) {
      float f = v[j];
      _Float16 hb = (_Float16)f;
      float hf = (float)hb;
      _Float16 lb = (_Float16)(f - hf);
      h[j]  = __builtin_bit_cast(unsigned short, hb);
      lw[j] = __builtin_bit_cast(unsigned short, lb);
    }
    *(ushort8*)(xh + (size_t)i * 8) = h;
    *(ushort8*)(xl + (size_t)i * 8) = lw;
    return;
  }
  int be = b - 8192;
  if (be < 17) {
    int i = be * 256 + tid;
    if (i < 4160) wsZero[i] = 0.0f;
  }
  int w    = tid >> 6;
  int lane = tid & 63;
  int row  = be * 4 + w;
  const float* r = emb + (size_t)row * NDIM + lane * 8;
  float4 a = *(const float4*)r;
  float4 bb = *(const float4*)(r + 4);
  float v[8] = {a.x, a.y, a.z, a.w, bb.x, bb.y, bb.z, bb.w};
  ushort8 h, lw;
  float sq = 0.0f;
  #pragma unroll
  for (int j = 0; j < 8; j++) {
    float f = v[j];
    sq += f * f;
    _Float16 hb = (_Float16)f;
    float hf = (float)hb;
    _Float16 lb = (_Float16)(f - hf);
    h[j]  = __builtin_bit_cast(unsigned short, hb);
    lw[j] = __builtin_bit_cast(unsigned short, lb);
  }
  size_t o = (size_t)row * NDIM + lane * 8;
  *(ushort8*)(eh + o) = h;
  *(ushort8*)(el + o) = lw;
  #pragma unroll
  for (int off = 32; off >= 1; off >>= 1) sq += __shfl_xor(sq, off, 64);
  if (lane == 0) e2[row] = sq;
}

// one wave per row: sum of squares (fallback path only)
__global__ void k_rowsq(const float* __restrict__ rows, float* __restrict__ out, int nrows) {
  int gw   = (blockIdx.x * blockDim.x + threadIdx.x) >> 6;
  int lane = threadIdx.x & 63;
  if (gw >= nrows) return;
  const float* r = rows + (size_t)gw * NDIM + lane * 8;
  float4 a = *(const float4*)r;
  float4 b = *(const float4*)(r + 4);
  float s = ((a.x*a.x + a.y*a.y) + (a.z*a.z + a.w*a.w))
          + ((b.x*b.x + b.y*b.y) + (b.z*b.z + b.w*b.w));
  #pragma unroll
  for (int off = 32; off >= 1; off >>= 1) s += __shfl_xor(s, off, 64);
  if (lane == 0) out[gw] = s;
}

// ===================== MFMA argmin (round-6 configuration — measured 454 us) =====================
// grid 256 = 128 token-panels (BM=256) x 2 code-halves (2048 each).
// half = (h>>2)&1, panel = (h>>3)*4 + (h&3).
// Block sweeps its half in 8 chunks of 256 codes; acc tile 256x256; 8 waves (wm4 x wn2).
// dist = e2 - 2*dot; dot = hh + hl + lh (3 f16 MFMAs). Single top-2 flush after the half.
#define SLOT 8192   // ushorts per LDS slot (256 rows x 32 k)
__launch_bounds__(512, 2)
__global__ void k_argmin_mfma(const unsigned short* __restrict__ xh, const unsigned short* __restrict__ xl,
                              const unsigned short* __restrict__ eh, const unsigned short* __restrict__ el,
                              const float* __restrict__ e2,
                              float* __restrict__ pd1, int* __restrict__ pi1,
                              float* __restrict__ pd2, int* __restrict__ pi2) {
  __shared__ __align__(16) unsigned short Ah[2 * SLOT];   // 32 KB (reused for reduction)
  __shared__ __align__(16) unsigned short Al[2 * SLOT];
  __shared__ __align__(16) unsigned short Bh[2 * SLOT];
  __shared__ __align__(16) unsigned short Bl[2 * SLOT];

  const int tid = threadIdx.x;
  const int w   = tid >> 6;
  const int l   = tid & 63;
  const int wm  = w >> 1;     // 0..3: 64-row group
  const int wn  = w & 1;      // 0..1: 128-col group
  const int l15 = l & 15;
  const int l4  = l >> 4;

  const int h     = blockIdx.x;
  const int half  = (h >> 2) & 1;
  const int panel = (h >> 3) * 4 + (h & 3);
  const int brow  = panel * 256;
  const int cbase = half * 2048;

  // fragment LDS offsets (ushort units), swizzled
  int aOff[4], bOff[8];
  #pragma unroll
  for (int mi = 0; mi < 4; mi++) aOff[mi] = swz16(((wm * 64 + mi * 16 + l15) << 2) | l4) * 8;
  #pragma unroll
  for (int nj = 0; nj < 8; nj++) bOff[nj] = swz16(((wn * 128 + nj * 16 + l15) << 2) | l4) * 8;

  // staging: linear LDS chunks {tid, tid+512}; swizzled (row,seg) source (involution)
  int sR[2], sS[2];
  #pragma unroll
  for (int q = 0; q < 2; q++) {
    int sc = swz16(tid + q * 512);
    sR[q] = sc >> 2; sS[q] = (sc & 3) * 8;
  }
  size_t aG[2];
  #pragma unroll
  for (int q = 0; q < 2; q++) aG[q] = (size_t)(brow + sR[q]) * NDIM + sS[q];

  float d1[16], d2[16];
  int   i1[16], i2[16];
  #pragma unroll
  for (int s = 0; s < 16; s++) { d1[s] = 1e30f; d2[s] = 1e30f; i1[s] = 0; i2[s] = 0; }

  auto STAGE = [&](int buf, int c0, int k0) {
    #pragma unroll
    for (int q = 0; q < 2; q++) {
      int dst = (tid + q * 512) * 8;
      gload16(xh + aG[q] + k0, Ah + buf * SLOT + dst);
      gload16(xl + aG[q] + k0, Al + buf * SLOT + dst);
      size_t bGq = (size_t)(c0 + sR[q]) * NDIM + k0 + sS[q];
      gload16(eh + bGq, Bh + buf * SLOT + dst);
      gload16(el + bGq, Bl + buf * SLOT + dst);
    }
  };

  STAGE(0, cbase, 0);
  int cur = 0;
  __syncthreads();

  for (int ci = 0; ci < 8; ci++) {
    const int c0 = cbase + ci * 256;
    f32x4 acc[4][8];
    #pragma unroll
    for (int mi = 0; mi < 4; mi++)
      #pragma unroll
      for (int nj = 0; nj < 8; nj++) acc[mi][nj] = (f32x4)0.0f;

    for (int kt = 0; kt < 16; kt++) {
      if (kt < 15)     STAGE(cur ^ 1, c0, (kt + 1) * 32);
      else if (ci < 7) STAGE(cur ^ 1, c0 + 256, 0);

      const unsigned short* AhC = Ah + cur * SLOT;
      const unsigned short* AlC = Al + cur * SLOT;
      const unsigned short* BhC = Bh + cur * SLOT;
      const unsigned short* BlC = Bl + cur * SLOT;

      f16x8 ah[4], al[4];
      #pragma unroll
      for (int mi = 0; mi < 4; mi++) {
        ah[mi] = *(const f16x8*)(const void*)(AhC + aOff[mi]);
        al[mi] = *(const f16x8*)(const void*)(AlC + aOff[mi]);
      }
      #pragma unroll
      for (int nj = 0; nj < 8; nj++) {
        f16x8 bh = *(const f16x8*)(const void*)(BhC + bOff[nj]);
        f16x8 bl = *(const f16x8*)(const void*)(BlC + bOff[nj]);
        #pragma unroll
        for (int mi = 0; mi < 4; mi++) {
          acc[mi][nj] = __builtin_amdgcn_mfma_f32_16x16x32_f16(ah[mi], bh, acc[mi][nj], 0, 0, 0);
          acc[mi][nj] = __builtin_amdgcn_mfma_f32_16x16x32_f16(ah[mi], bl, acc[mi][nj], 0, 0, 0);
          acc[mi][nj] = __builtin_amdgcn_mfma_f32_16x16x32_f16(al[mi], bh, acc[mi][nj], 0, 0, 0);
        }
      }
      __syncthreads();
      cur ^= 1;
    }

    // top-2 update for this 256-code chunk (accumulates across the whole half)
    #pragma unroll
    for (int nj = 0; nj < 8; nj++) {
      int col  = c0 + wn * 128 + nj * 16 + l15;
      float ev = e2[col];
      #pragma unroll
      for (int mi = 0; mi < 4; mi++) {
        #pragma unroll
        for (int r = 0; r < 4; r++) {
          float d = ev - 2.0f * acc[mi][nj][r];
          int s = mi * 4 + r;
          if (d < d1[s]) { d2[s] = d1[s]; i2[s] = i1[s]; d1[s] = d; i1[s] = col; }
          else if (d < d2[s]) { d2[s] = d; i2[s] = col; }
        }
      }
    }
  }

  // butterfly merge across the 16 column-lanes
  #pragma unroll
  for (int off = 8; off >= 1; off >>= 1) {
    #pragma unroll
    for (int s = 0; s < 16; s++) {
      float od1 = __shfl_xor(d1[s], off, 16);
      int   oi1 = __shfl_xor(i1[s], off, 16);
      float od2 = __shfl_xor(d2[s], off, 16);
      int   oi2 = __shfl_xor(i2[s], off, 16);
      mergePair(d1[s], i1[s], d2[s], i2[s], od1, oi1, od2, oi2);
    }
  }

  // reduce across the 2 wn groups via LDS (reuse Ah region: 8 KB of 32 KB)
  float* redD1 = (float*)Ah;           // [2][256]
  int*   redI1 = (int*)Ah + 512;
  float* redD2 = (float*)Ah + 1024;
  int*   redI2 = (int*)Ah + 1536;
  __syncthreads();
  if (l15 == 0) {
    #pragma unroll
    for (int s = 0; s < 16; s++) {
      int rowLocal = wm * 64 + (s >> 2) * 16 + l4 * 4 + (s & 3);
      redD1[wn * 256 + rowLocal] = d1[s];
      redI1[wn * 256 + rowLocal] = i1[s];
      redD2[wn * 256 + rowLocal] = d2[s];
      redI2[wn * 256 + rowLocal] = i2[s];
    }
  }
  __syncthreads();
  if (tid < 256) {
    float a1 = redD1[tid], a2 = redD2[tid];
    int   x1 = redI1[tid], x2 = redI2[tid];
    mergePair(a1, x1, a2, x2, redD1[256 + tid], redI1[256 + tid], redD2[256 + tid], redI2[256 + tid]);
    size_t o = (size_t)half * NTOK + brow + tid;
    pd1[o] = a1; pi1[o] = x1; pd2[o] = a2; pi2[o] = x2;
  }
}

// merge halves -> idxArr + codes + hist; pair-recheck flagged tokens in-block (f64),
// fixing idx/codes/hist for flipped tokens.
__global__ void k_combine_recheck(const float* __restrict__ pd1, const int* __restrict__ pi1,
                                  const float* __restrict__ pd2, const int* __restrict__ pi2,
                                  const float* __restrict__ x, const float* __restrict__ emb,
                                  int* __restrict__ idxArr, float* __restrict__ codesOut,
                                  int* __restrict__ histI) {
  __shared__ int fT[256], fC1[256], fC2[256];
  __shared__ int fcnt;
  int tid = threadIdx.x;
  int t   = blockIdx.x * 256 + tid;
  if (tid == 0) fcnt = 0;
  __syncthreads();

  float a1 = pd1[t], a2 = pd2[t];
  int   x1 = pi1[t], x2 = pi2[t];
  mergePair(a1, x1, a2, x2, pd1[NTOK + t], pi1[NTOK + t], pd2[NTOK + t], pi2[NTOK + t]);
  idxArr[t]   = x1;
  codesOut[t] = (float)x1;
  atomicAdd(histI + x1, 1);
  if (a2 - a1 < TAU) {
    int slot = atomicAdd(&fcnt, 1);
    fT[slot] = t; fC1[slot] = x1; fC2[slot] = x2;
  }
  __syncthreads();

  int n  = fcnt;
  int wv = tid >> 6, lane = tid & 63;
  for (int ti = wv; ti < n; ti += 4) {
    int tt = fT[ti], c1 = fC1[ti], c2 = fC2[ti];
    const float* xr = x   + (size_t)tt * NDIM + lane * 8;
    const float* e1 = emb + (size_t)c1 * NDIM + lane * 8;
    const float* e2 = emb + (size_t)c2 * NDIM + lane * 8;
    double s1 = 0.0, s2 = 0.0;
    #pragma unroll
    for (int j = 0; j < 8; j++) {
      double xv = (double)xr[j];
      double a = (double)e1[j];
      double b = (double)e2[j];
      s1 += a * (a - 2.0 * xv);
      s2 += b * (b - 2.0 * xv);
    }
    #pragma unroll
    for (int off = 32; off >= 1; off >>= 1) {
      s1 += __shfl_xor(s1, off, 64);
      s2 += __shfl_xor(s2, off, 64);
    }
    if (lane == 0) {
      bool take2 = (s2 < s1) || (s2 == s1 && c2 < c1);
      if (take2) {
        idxArr[tt]   = c2;
        codesOut[tt] = (float)c2;
        atomicAdd(histI + c2, 1);
        atomicAdd(histI + c1, -1);
      }
    }
  }
}

// ===================== fallback f32 argmin (small-ws path) =====================
#define BM 64
#define BN 64
#define BK 32
__launch_bounds__(256)
__global__ void k_argmin_f32(const float* __restrict__ x, const float* __restrict__ emb,
                             const float* __restrict__ e2, int* __restrict__ idxOut,
                             float* __restrict__ codesOut, int* __restrict__ histI) {
  __shared__ __align__(16) float xs[BK][BM + 4];
  __shared__ __align__(16) float es[BK][BN + 4];
  const int tid  = threadIdx.x;
  const int tx   = tid & 15;
  const int ty   = tid >> 4;
  const int brow = blockIdx.x * BM;
  const int lk   = tid & 7;
  const int lr   = tid >> 3;

  double best[4];
  int    bidx[4];
  #pragma unroll
  for (int i = 0; i < 4; i++) { best[i] = 1e300; bidx[i] = 0; }

  for (int c0 = 0; c0 < NCODE; c0 += BN) {
    float acc[4][4];
    #pragma unroll
    for (int i = 0; i < 4; i++)
      #pragma unroll
      for (int j = 0; j < 4; j++) acc[i][j] = 0.0f;
    for (int k0 = 0; k0 < NDIM; k0 += BK) {
      __syncthreads();
      float4 v0 = *(const float4*)&x  [(size_t)(brow + lr)      * NDIM + k0 + lk * 4];
      float4 v1 = *(const float4*)&x  [(size_t)(brow + lr + 32) * NDIM + k0 + lk * 4];
      float4 w0 = *(const float4*)&emb[(size_t)(c0   + lr)      * NDIM + k0 + lk * 4];
      float4 w1 = *(const float4*)&emb[(size_t)(c0   + lr + 32) * NDIM + k0 + lk * 4];
      float a0[4] = {v0.x, v0.y, v0.z, v0.w};
      float a1[4] = {v1.x, v1.y, v1.z, v1.w};
      float b0[4] = {w0.x, w0.y, w0.z, w0.w};
      float b1f[4] = {w1.x, w1.y, w1.z, w1.w};
      #pragma unroll
      for (int j = 0; j < 4; j++) {
        xs[lk * 4 + j][lr]      = a0[j];
        xs[lk * 4 + j][lr + 32] = a1[j];
        es[lk * 4 + j][lr]      = b0[j];
        es[lk * 4 + j][lr + 32] = b1f[j];
      }
      __syncthreads();
      #pragma unroll
      for (int k = 0; k < BK; k++) {
        const float4 av = *(const float4*)&xs[k][ty * 4];
        const float4 bv = *(const float4*)&es[k][tx * 4];
        const float ax[4] = {av.x, av.y, av.z, av.w};
        const float bx[4] = {bv.x, bv.y, bv.z, bv.w};
        #pragma unroll
        for (int i = 0; i < 4; i++)
          #pragma unroll
          for (int j = 0; j < 4; j++) acc[i][j] += ax[i] * bx[j];
      }
    }
    #pragma unroll
    for (int j = 0; j < 4; j++) {
      float e2v = e2[c0 + tx * 4 + j];
      int   ci  = c0 + tx * 4 + j;
      #pragma unroll
      for (int i = 0; i < 4; i++) {
        double d = (double)e2v - 2.0 * (double)acc[i][j];
        if (d < best[i]) { best[i] = d; bidx[i] = ci; }
      }
    }
  }
  #pragma unroll
  for (int off = 8; off >= 1; off >>= 1) {
    #pragma unroll
    for (int i = 0; i < 4; i++) {
      double ob = __shfl_xor(best[i], off, 16);
      int    oi = __shfl_xor(bidx[i], off, 16);
      if (ob < best[i] || (ob == best[i] && oi < bidx[i])) { best[i] = ob; bidx[i] = oi; }
    }
  }
  if (tx == 0) {
    #pragma unroll
    for (int i = 0; i < 4; i++) {
      int t = brow + ty * 4 + i;
      idxOut[t]   = bidx[i];
      codesOut[t] = (float)bidx[i];
      atomicAdd(histI + bidx[i], 1);
    }
  }
}

// one wave per token: z[t] = emb[idx[t]]  (z == quantize exactly; no x read needed)
__global__ void k_zwrite(const float* __restrict__ emb, const int* __restrict__ idxArr,
                         float* __restrict__ z) {
  int t    = (blockIdx.x * blockDim.x + threadIdx.x) >> 6;
  int lane = threadIdx.x & 63;
  if (t >= NTOK) return;
  int idx = idxArr[t];
  const float* er = emb + (size_t)idx * NDIM + lane * 8;
  float*       zr = z   + (size_t)t   * NDIM + lane * 8;
  float4 q0 = *(const float4*)er;
  float4 q1 = *(const float4*)(er + 4);
  *(float4*)zr       = q0;
  *(float4*)(zr + 4) = q1;
}

// single block: prefix-scan over hist + new_size/scalars (diff written later by k_fin)
__global__ void k_scanstats(const int* __restrict__ histI, int* __restrict__ offs,
                            int* __restrict__ cursor, const float* __restrict__ clusterSize,
                            float* __restrict__ out, float* __restrict__ nOut) {
  __shared__ int part[256];
  int tid = threadIdx.x;
  int base = tid * 16;
  int local[16];
  int s = 0;
  #pragma unroll
  for (int j = 0; j < 16; j++) { local[j] = s; s += histI[base + j]; }
  part[tid] = s;
  __syncthreads();
  for (int off = 1; off < 256; off <<= 1) {
    int v = 0;
    if (tid >= off) v = part[tid - off];
    __syncthreads();
    part[tid] += v;
    __syncthreads();
  }
  int pre = (tid == 0) ? 0 : part[tid - 1];
  #pragma unroll
  for (int j = 0; j < 16; j++) {
    int o = pre + local[j];
    offs[base + j]   = o;
    cursor[base + j] = o;
  }

  const float OMD = (float)(1.0 - 0.995);
  float ln = 0.0f, lu = 0.0f, le = 0.0f;
  for (int i = tid; i < NCODE; i += 256) {
    float c  = (float)histI[i];
    float ns = 0.995f * clusterSize[i] + OMD * c;
    out[OFF_SIZE + i] = ns;
    ln += ns;
    if (ns >= 0.99f) lu += 1.0f;
    float pr = c * (1.0f / 32768.0f);
    le += pr * logf(pr + 1e-5f);
  }
  #pragma unroll
  for (int off = 32; off >= 1; off >>= 1) {
    ln += __shfl_xor(ln, off, 64);
    lu += __shfl_xor(lu, off, 64);
    le += __shfl_xor(le, off, 64);
  }
  __shared__ float sn[4], su[4], se[4];
  int w = tid >> 6;
  if ((tid & 63) == 0) { sn[w] = ln; su[w] = lu; se[w] = le; }
  __syncthreads();
  if (tid == 0) {
    float n = (sn[0] + sn[1]) + (sn[2] + sn[3]);
    float u = (su[0] + su[1]) + (su[2] + su[3]);
    float e = (se[0] + se[1]) + (se[2] + se[3]);
    nOut[0] = n;
    out[OFF_AVGU]  = u * (1.0f / 4096.0f);
    out[OFF_USAGE] = u;
    out[OFF_ENT]   = -e;
  }
}

// scatter token ids into code-sorted order
__global__ void k_scatter(const int* __restrict__ idxArr, int* __restrict__ cursor,
                          int* __restrict__ sorted) {
  int t = blockIdx.x * blockDim.x + threadIdx.x;
  if (t >= NTOK) return;
  int p = atomicAdd(cursor + idxArr[t], 1);
  sorted[p] = t;
}

// one block per code: raw csum + EMA + embedding + diff partial in one pass
__global__ void k_csumfinal(const float* __restrict__ x, const int* __restrict__ offs,
                            const int* __restrict__ histI, const int* __restrict__ sorted,
                            const float* __restrict__ emb,
                            const float* __restrict__ clusterSum, const float* __restrict__ newSize,
                            const float* __restrict__ nPtr, float* __restrict__ sumOut,
                            float* __restrict__ embOut, float* __restrict__ diffSum) {
  __shared__ int sidx[1024];
  __shared__ float dred[4];
  int c   = blockIdx.x;
  int tid = threadIdx.x;
  int o = offs[c], n = histI[c];
  float ec0 = emb[(size_t)c * NDIM + tid];
  float ec1 = emb[(size_t)c * NDIM + tid + 256];
  float a0 = 0.0f, a1 = 0.0f, dsum = 0.0f;
  for (int base = 0; base < n; base += 1024) {
    int m = min(n - base, 1024);
    __syncthreads();
    for (int j = tid; j < m; j += 256) sidx[j] = sorted[o + base + j];
    __syncthreads();
    for (int j = 0; j < m; j++) {
      const float* xr = x + (size_t)sidx[j] * NDIM;
      float v0 = xr[tid];
      float v1 = xr[tid + 256];
      a0 += v0;
      a1 += v1;
      float q0 = ec0 - v0;
      float q1 = ec1 - v1;
      dsum += q0 * q0 + q1 * q1;
    }
  }
  // block-reduce dsum -> one atomic
  #pragma unroll
  for (int off = 32; off >= 1; off >>= 1) dsum += __shfl_xor(dsum, off, 64);
  int wv = tid >> 6;
  if ((tid & 63) == 0) dred[wv] = dsum;
  __syncthreads();
  if (tid == 0) atomAddF(diffSum, (dred[0] + dred[1]) + (dred[2] + dred[3]));

  const float OMD = (float)(1.0 - 0.995);
  float nv  = nPtr[0];
  float sz  = newSize[c];
  float cnt = (sz + 1e-4f) / (nv + 0.4096f) * nv;
  float rc  = (sz >= 0.99f) ? (1.0f / cnt) : 0.0f;
  size_t i0 = (size_t)c * NDIM + tid;
  size_t i1 = i0 + 256;
  float ns0 = 0.995f * clusterSum[i0] + OMD * a0;
  float ns1 = 0.995f * clusterSum[i1] + OMD * a1;
  sumOut[i0] = ns0;
  sumOut[i1] = ns1;
  embOut[i0] = ns0 * rc;
  embOut[i1] = ns1 * rc;
}

// finalize diff scalar
__global__ void k_fin(const float* __restrict__ diffSum, float* __restrict__ out) {
  if (threadIdx.x == 0) out[OFF_DIFF] = diffSum[0] * (1.0f / 16777216.0f);
}

extern "C" void kernel_launch(void* const* d_in, const int* in_sizes, int n_in,
                              void* d_out, int out_size, void* d_ws, size_t ws_size,
                              hipStream_t stream) {
  const float* x   = (const float*)d_in[0];
  const float* emb = (const float*)d_in[1];
  const float* csz = (const float*)d_in[2];
  const float* csm = (const float*)d_in[3];
  float* out = (float*)d_out;

  float* wsf     = (float*)d_ws;
  float* diffSum = wsf;                      // [0]
  float* nScal   = wsf + 1;                  // [1]
  int*   histI   = (int*)(wsf + 64);         // 4096
  int*   offs    = histI + NCODE;            // 4096
  int*   cursor  = offs + NCODE;             // 4096
  float* e2      = (float*)(cursor + NCODE); // 4096
  int*   idxArr  = (int*)(e2 + NCODE);       // 32768
  int*   sorted  = idxArr + NTOK;            // 32768
  float* pd1     = (float*)(sorted + NTOK);  // 2*32768
  int*   pi1     = (int*)(pd1 + 2 * NTOK);   // 2*32768
  float* pd2     = (float*)(pi1 + 2 * NTOK); // 2*32768
  int*   pi2     = (int*)(pd2 + 2 * NTOK);   // 2*32768
  unsigned short* xh = (unsigned short*)(pi2 + 2 * NTOK);
  unsigned short* xl = xh + (size_t)NTOK * NDIM;
  unsigned short* eh = xl + (size_t)NTOK * NDIM;
  unsigned short* el = eh + (size_t)NCODE * NDIM;

  const size_t need = (size_t)((char*)(el + (size_t)NCODE * NDIM) - (char*)d_ws);

  if (ws_size >= need) {
    k_prep<<<9216, 256, 0, stream>>>(x, emb, xh, xl, eh, el, e2, wsf);
    k_argmin_mfma<<<256, 512, 0, stream>>>(xh, xl, eh, el, e2, pd1, pi1, pd2, pi2);
    k_combine_recheck<<<NTOK / 256, 256, 0, stream>>>(pd1, pi1, pd2, pi2, x, emb, idxArr,
                                                      out + OFF_CODES, histI);
  } else {
    k_zero<<<(64 + NCODE + 255) / 256, 256, 0, stream>>>(wsf, 64 + NCODE);
    k_rowsq<<<NCODE / 4, 256, 0, stream>>>(emb, e2, NCODE);
    k_argmin_f32<<<NTOK / BM, 256, 0, stream>>>(x, emb, e2, idxArr, out + OFF_CODES, histI);
  }

  k_zwrite<<<NTOK / 4, 256, 0, stream>>>(emb, idxArr, out + OFF_Z);
  k_scanstats<<<1, 256, 0, stream>>>(histI, offs, cursor, csz, out, nScal);
  k_scatter<<<NTOK / 256, 256, 0, stream>>>(idxArr, cursor, sorted);
  k_csumfinal<<<NCODE, 256, 0, stream>>>(x, offs, histI, sorted, emb, csm, out + OFF_SIZE, nScal,
                                         out + OFF_SUM, out + OFF_EMB, diffSum);
  k_fin<<<1, 64, 0, stream>>>(diffSum, out);
}